// Round 1
// baseline (831.139 us; speedup 1.0000x reference)
//
#include <hip/hip_runtime.h>
#include <math.h>

#define L 2048
#define DM 512
#define B_ 8
#define H_ 8
#define DH 64
#define SK 24
#define NTOP 24

// ---------------- reduce helpers ----------------
__device__ inline float waveReduceSum(float v) {
    for (int o = 32; o > 0; o >>= 1) v += __shfl_down(v, o, 64);
    return v;
}
__device__ inline float waveReduceMax(float v) {
    for (int o = 32; o > 0; o >>= 1) v = fmaxf(v, __shfl_down(v, o, 64));
    return v;
}

// ---------------- LayerNorm (row-wise, 512 cols) ----------------
__global__ __launch_bounds__(256)
void ln_kernel(const float* __restrict__ x, const float* __restrict__ w,
               const float* __restrict__ bvec, float* __restrict__ out) {
    int row = blockIdx.x;
    const float* xr = x + (size_t)row * DM;
    float* orow = out + (size_t)row * DM;
    int tid = threadIdx.x;
    float2 v = *(const float2*)(xr + tid * 2);
    float s = v.x + v.y;
    float sq = v.x * v.x + v.y * v.y;
    __shared__ float red[8];
    float ws = waveReduceSum(s);
    float wq = waveReduceSum(sq);
    int wid = tid >> 6, lane = tid & 63;
    if (lane == 0) { red[wid] = ws; red[4 + wid] = wq; }
    __syncthreads();
    float tot = red[0] + red[1] + red[2] + red[3];
    float totq = red[4] + red[5] + red[6] + red[7];
    float mean = tot * (1.0f / DM);
    float var = totq * (1.0f / DM) - mean * mean;
    float inv = rsqrtf(var + 1e-8f);
    float w0 = w[tid * 2], w1 = w[tid * 2 + 1];
    float b0 = bvec[tid * 2], b1 = bvec[tid * 2 + 1];
    float2 o;
    o.x = w0 * (v.x - mean) * inv + b0;
    o.y = w1 * (v.y - mean) * inv + b1;
    *(float2*)(orow + tid * 2) = o;
}

// ---------------- f32 GEMM: C[M x 512] = A[M x 512] @ W[512 x 512] + bias ----------------
#define GBM 128
#define GBN 128
#define GBK 16

__global__ __launch_bounds__(256)
void gemm512(const float* __restrict__ A, const float* __restrict__ W,
             const float* __restrict__ bias, float* __restrict__ C) {
    __shared__ float As[GBK][GBM + 4];
    __shared__ float Bs[GBK][GBN + 4];
    int m0 = blockIdx.y * GBM;
    int n0 = blockIdx.x * GBN;
    int tid = threadIdx.x;
    int tn = tid & 15, tm = tid >> 4;
    float acc[8][8];
#pragma unroll
    for (int i = 0; i < 8; i++)
#pragma unroll
        for (int j = 0; j < 8; j++) acc[i][j] = 0.f;

    for (int k0 = 0; k0 < 512; k0 += GBK) {
#pragma unroll
        for (int l = 0; l < 2; l++) {
            int f = tid + l * 256;            // 0..511 float4s of A tile
            int row = f >> 2, ks = (f & 3) * 4;
            float4 a = *(const float4*)(A + (size_t)(m0 + row) * 512 + k0 + ks);
            As[ks + 0][row] = a.x;
            As[ks + 1][row] = a.y;
            As[ks + 2][row] = a.z;
            As[ks + 3][row] = a.w;
        }
#pragma unroll
        for (int l = 0; l < 2; l++) {
            int f = tid + l * 256;            // 0..511 float4s of W tile
            int row = f >> 5, ns = (f & 31) * 4;
            *(float4*)(&Bs[row][ns]) = *(const float4*)(W + (size_t)(k0 + row) * 512 + n0 + ns);
        }
        __syncthreads();
#pragma unroll
        for (int kk = 0; kk < GBK; kk++) {
            float a[8], b[8];
#pragma unroll
            for (int i = 0; i < 8; i++) a[i] = As[kk][tm * 8 + i];
#pragma unroll
            for (int j = 0; j < 8; j++) b[j] = Bs[kk][tn * 8 + j];
#pragma unroll
            for (int i = 0; i < 8; i++)
#pragma unroll
                for (int j = 0; j < 8; j++)
                    acc[i][j] = fmaf(a[i], b[j], acc[i][j]);
        }
        __syncthreads();
    }
#pragma unroll
    for (int i = 0; i < 8; i++) {
        int m = m0 + tm * 8 + i;
#pragma unroll
        for (int j = 0; j < 8; j++) {
            int n = n0 + tn * 8 + j;
            C[(size_t)m * 512 + n] = acc[i][j] + bias[n];
        }
    }
}

// ---------------- sampled QK^T -> M ----------------
__global__ __launch_bounds__(256)
void sample_m_kernel(const float* __restrict__ q, const float* __restrict__ k,
                     const int* __restrict__ idx, float* __restrict__ M) {
    int i = blockIdx.x;   // query position
    int b = blockIdx.y;
    __shared__ float kb[SK][DM + 4];
    __shared__ float qs[DM];
    __shared__ float dots[H_][SK];
    int tid = threadIdx.x;
    if (tid < 128) {
        *(float4*)(&qs[tid * 4]) = *(const float4*)(q + ((size_t)b * L + i) * DM + tid * 4);
    }
#pragma unroll
    for (int l = 0; l < 12; l++) {
        int f = tid + l * 256;               // 0..3071 float4s
        int r = f >> 7, seg = (f & 127) * 4;
        int row = idx[i * SK + r];
        *(float4*)(&kb[r][seg]) = *(const float4*)(k + ((size_t)b * L + row) * DM + seg);
    }
    __syncthreads();
    if (tid < H_ * SK) {
        int h = tid / SK, j = tid % SK;
        float s = 0.f;
        const float* qp = qs + h * DH;
        const float* kp = &kb[j][h * DH];
#pragma unroll
        for (int d = 0; d < DH; d++) s = fmaf(qp[d], kp[d], s);
        dots[h][j] = s;
    }
    __syncthreads();
    if (tid < H_) {
        float mx = -1e30f, sm = 0.f;
#pragma unroll
        for (int j = 0; j < SK; j++) { float v = dots[tid][j]; mx = fmaxf(mx, v); sm += v; }
        M[((size_t)b * H_ + tid) * L + i] = mx - sm * (1.0f / L);
    }
}

// ---------------- top-24 per (b,h), low-index tie-break ----------------
__global__ __launch_bounds__(256)
void topk_kernel(const float* __restrict__ M, int* __restrict__ mtop) {
    int bh = blockIdx.x;
    __shared__ float vals[L];
    __shared__ float rv[4];
    __shared__ int ri[4];
    int tid = threadIdx.x;
    const float* Mr = M + (size_t)bh * L;
    for (int t = tid; t < L; t += 256) vals[t] = Mr[t];
    __syncthreads();
    for (int it = 0; it < NTOP; it++) {
        float bv = -1e30f; int bi = 0x7fffffff;
        for (int t = tid; t < L; t += 256) {
            float v = vals[t];
            if (v > bv || (v == bv && t < bi)) { bv = v; bi = t; }
        }
        for (int o = 32; o > 0; o >>= 1) {
            float ov = __shfl_down(bv, o, 64);
            int oi = __shfl_down(bi, o, 64);
            if (ov > bv || (ov == bv && oi < bi)) { bv = ov; bi = oi; }
        }
        int wid = tid >> 6, lane = tid & 63;
        if (lane == 0) { rv[wid] = bv; ri[wid] = bi; }
        __syncthreads();
        if (tid == 0) {
            float fbv = rv[0]; int fbi = ri[0];
            for (int wv = 1; wv < 4; wv++)
                if (rv[wv] > fbv || (rv[wv] == fbv && ri[wv] < fbi)) { fbv = rv[wv]; fbi = ri[wv]; }
            mtop[bh * NTOP + it] = fbi;
            vals[fbi] = -1e30f;
        }
        __syncthreads();
    }
}

// ---------------- padding cumsum ----------------
__global__ __launch_bounds__(256)
void padscan_kernel(const float* __restrict__ pad, float* __restrict__ denom) {
    int b = blockIdx.x;
    __shared__ float tot[256];
    int tid = threadIdx.x;
    const float* p = pad + (size_t)b * L;
    float loc[8];
    float s = 0.f;
#pragma unroll
    for (int u = 0; u < 8; u++) { s += p[tid * 8 + u]; loc[u] = s; }
    tot[tid] = s;
    __syncthreads();
    for (int off = 1; off < 256; off <<= 1) {
        float add = (tid >= off) ? tot[tid - off] : 0.f;
        __syncthreads();
        tot[tid] += add;
        __syncthreads();
    }
    float excl = tot[tid] - s;
#pragma unroll
    for (int u = 0; u < 8; u++) denom[(size_t)b * L + tid * 8 + u] = excl + loc[u];
}

// ---------------- cumulative average of V (3 passes) ----------------
__global__ __launch_bounds__(512)
void vavg1_kernel(const float* __restrict__ v, float* __restrict__ pre, float* __restrict__ csum) {
    int c = blockIdx.x, b = blockIdx.y, d = threadIdx.x;
    size_t base = ((size_t)b * L + c * 128) * DM + d;
    float acc = 0.f;
    for (int t = 0; t < 128; t++) {
        acc += v[base + (size_t)t * DM];
        pre[base + (size_t)t * DM] = acc;
    }
    csum[((size_t)b * 16 + c) * DM + d] = acc;
}

__global__ __launch_bounds__(512)
void vavg2_kernel(float* __restrict__ csum) {
    int b = blockIdx.x, d = threadIdx.x;
    float run = 0.f;
    for (int c = 0; c < 16; c++) {
        size_t o = ((size_t)b * 16 + c) * DM + d;
        float t = csum[o];
        csum[o] = run;
        run += t;
    }
}

__global__ __launch_bounds__(512)
void vavg3_kernel(float* __restrict__ pre, const float* __restrict__ csum,
                  const float* __restrict__ denom) {
    int c = blockIdx.x, b = blockIdx.y, d = threadIdx.x;
    float off = csum[((size_t)b * 16 + c) * DM + d];
    size_t base = ((size_t)b * L + c * 128) * DM + d;
    for (int t = 0; t < 128; t++) {
        float dn = denom[(size_t)b * L + c * 128 + t] + 1e-12f;
        pre[base + (size_t)t * DM] = (pre[base + (size_t)t * DM] + off) / dn;
    }
}

// ---------------- sparse attention for selected rows + scatter ----------------
__global__ __launch_bounds__(256)
void attn_kernel(const float* __restrict__ q, const float* __restrict__ k,
                 const float* __restrict__ v, const int* __restrict__ mtop,
                 const float* __restrict__ pad, float* __restrict__ pre) {
    int u = blockIdx.x, h = blockIdx.y, b = blockIdx.z;
    int bh = b * H_ + h;
    int iq = mtop[bh * NTOP + u];
    bool padok = pad[(size_t)b * L + iq] != 0.f;
    __shared__ float qs[DH];
    __shared__ float ps[L];
    __shared__ float outs[4][DH];
    __shared__ float red[4];
    int tid = threadIdx.x;
    if (tid < 16) {
        *(float4*)(&qs[tid * 4]) = *(const float4*)(q + ((size_t)b * L + iq) * DM + h * DH + tid * 4);
    }
    __syncthreads();
    const float scale = 0.044194173824159216f;  // 1/sqrt(512)
    int d = tid & 63, g = tid >> 6;
    if (padok) {
        float lmax = -1e30f;
        for (int j = tid; j <= iq; j += 256) {
            const float* kp = k + ((size_t)b * L + j) * DM + h * DH;
            float s = 0.f;
#pragma unroll
            for (int dd = 0; dd < DH; dd += 4) {
                float4 kv = *(const float4*)(kp + dd);
                s = fmaf(qs[dd], kv.x, s);
                s = fmaf(qs[dd + 1], kv.y, s);
                s = fmaf(qs[dd + 2], kv.z, s);
                s = fmaf(qs[dd + 3], kv.w, s);
            }
            s *= scale;
            ps[j] = s;
            lmax = fmaxf(lmax, s);
        }
        lmax = waveReduceMax(lmax);
        if ((tid & 63) == 0) red[tid >> 6] = lmax;
        __syncthreads();
        float smax = fmaxf(fmaxf(red[0], red[1]), fmaxf(red[2], red[3]));
        float lsum = 0.f;
        for (int j = tid; j <= iq; j += 256) {
            float e = expf(ps[j] - smax);
            ps[j] = e;
            lsum += e;
        }
        lsum = waveReduceSum(lsum);
        __syncthreads();  // everyone done reading red (smax) & writing ps
        if ((tid & 63) == 0) red[tid >> 6] = lsum;
        __syncthreads();
        float ssum = red[0] + red[1] + red[2] + red[3];
        float acc = 0.f;
        for (int j = g; j <= iq; j += 4)
            acc = fmaf(ps[j], v[((size_t)b * L + j) * DM + h * DH + d], acc);
        outs[g][d] = acc;
        __syncthreads();
        if (tid < DH) {
            float o = (outs[0][tid] + outs[1][tid] + outs[2][tid] + outs[3][tid]) / ssum;
            pre[((size_t)b * L + iq) * DM + h * DH + tid] = o;
        }
    } else {
        float acc = 0.f;
        for (int j = g; j < L; j += 4)
            acc += v[((size_t)b * L + j) * DM + h * DH + d];
        outs[g][d] = acc;
        __syncthreads();
        if (tid < DH) {
            float o = (outs[0][tid] + outs[1][tid] + outs[2][tid] + outs[3][tid]) * (1.0f / L);
            pre[((size_t)b * L + iq) * DM + h * DH + tid] = o;
        }
    }
}

extern "C" void kernel_launch(void* const* d_in, const int* in_sizes, int n_in,
                              void* d_out, int out_size, void* d_ws, size_t ws_size,
                              hipStream_t stream) {
    const float* queries = (const float*)d_in[0];
    const float* keys    = (const float*)d_in[1];
    const float* values  = (const float*)d_in[2];
    const float* pad     = (const float*)d_in[3];
    const float* Wq = (const float*)d_in[4];  const float* bq = (const float*)d_in[5];
    const float* Wk = (const float*)d_in[6];  const float* bk = (const float*)d_in[7];
    const float* Wv = (const float*)d_in[8];  const float* bv = (const float*)d_in[9];
    const float* Wf = (const float*)d_in[10]; const float* bf = (const float*)d_in[11];
    const float* qlnw = (const float*)d_in[12]; const float* qlnb = (const float*)d_in[13];
    const float* flnw = (const float*)d_in[14]; const float* flnb = (const float*)d_in[15];
    const int* idx = (const int*)d_in[16];

    float* ws = (float*)d_ws;
    const size_t NE = (size_t)B_ * L * DM;   // 8388608
    float* qb    = ws;
    float* kb    = ws + NE;
    float* vb    = ws + 2 * NE;
    float* pre   = ws + 3 * NE;
    float* Mbuf  = ws + 4 * NE;                      // 64*2048
    float* denom = Mbuf + (size_t)B_ * H_ * L;       // 8*2048
    float* csum  = denom + (size_t)B_ * L;           // 8*16*512
    int*   mtop  = (int*)(csum + (size_t)B_ * 16 * DM);
    float* tmp   = (float*)d_out;  // reuse output buffer as LN/GEMM scratch

    padscan_kernel<<<B_, 256, 0, stream>>>(pad, denom);
    ln_kernel<<<B_ * L, 256, 0, stream>>>(queries, qlnw, qlnb, tmp);
    dim3 gg(4, 128);
    gemm512<<<gg, 256, 0, stream>>>(tmp, Wq, bq, qb);
    gemm512<<<gg, 256, 0, stream>>>(keys, Wk, bk, kb);
    gemm512<<<gg, 256, 0, stream>>>(values, Wv, bv, vb);
    dim3 gm(L, B_);
    sample_m_kernel<<<gm, 256, 0, stream>>>(qb, kb, idx, Mbuf);
    topk_kernel<<<B_ * H_, 256, 0, stream>>>(Mbuf, mtop);
    dim3 gv(16, B_);
    vavg1_kernel<<<gv, 512, 0, stream>>>(vb, pre, csum);
    vavg2_kernel<<<B_, 512, 0, stream>>>(csum);
    vavg3_kernel<<<gv, 512, 0, stream>>>(pre, csum, denom);
    dim3 ga(NTOP, H_, B_);
    attn_kernel<<<ga, 256, 0, stream>>>(qb, kb, vb, mtop, pad, pre);
    gemm512<<<gg, 256, 0, stream>>>(pre, Wf, bf, tmp);
    ln_kernel<<<B_ * L, 256, 0, stream>>>(tmp, flnw, flnb, (float*)d_out);
}

// Round 2
// 646.726 us; speedup vs baseline: 1.2851x; 1.2851x over previous
//
#include <hip/hip_runtime.h>
#include <math.h>

#define L 2048
#define DM 512
#define B_ 8
#define H_ 8
#define DH 64
#define SK 24
#define NTOP 24
#define CHUNK 128
#define NCH (L / CHUNK)   // 16

// ---------------- reduce helpers ----------------
__device__ inline float waveReduceSum(float v) {
    for (int o = 32; o > 0; o >>= 1) v += __shfl_down(v, o, 64);
    return v;
}
__device__ inline float waveReduceMax(float v) {
    for (int o = 32; o > 0; o >>= 1) v = fmaxf(v, __shfl_down(v, o, 64));
    return v;
}

// ---------------- LayerNorm (row-wise, 512 cols) ----------------
__global__ __launch_bounds__(256)
void ln_kernel(const float* __restrict__ x, const float* __restrict__ w,
               const float* __restrict__ bvec, float* __restrict__ out) {
    int row = blockIdx.x;
    const float* xr = x + (size_t)row * DM;
    float* orow = out + (size_t)row * DM;
    int tid = threadIdx.x;
    float2 v = *(const float2*)(xr + tid * 2);
    float s = v.x + v.y;
    float sq = v.x * v.x + v.y * v.y;
    __shared__ float red[8];
    float ws = waveReduceSum(s);
    float wq = waveReduceSum(sq);
    int wid = tid >> 6, lane = tid & 63;
    if (lane == 0) { red[wid] = ws; red[4 + wid] = wq; }
    __syncthreads();
    float tot = red[0] + red[1] + red[2] + red[3];
    float totq = red[4] + red[5] + red[6] + red[7];
    float mean = tot * (1.0f / DM);
    float var = totq * (1.0f / DM) - mean * mean;
    float inv = rsqrtf(var + 1e-8f);
    float w0 = w[tid * 2], w1 = w[tid * 2 + 1];
    float b0 = bvec[tid * 2], b1 = bvec[tid * 2 + 1];
    float2 o;
    o.x = w0 * (v.x - mean) * inv + b0;
    o.y = w1 * (v.y - mean) * inv + b1;
    *(float2*)(orow + tid * 2) = o;
}

// ---------------- f32 GEMM: C[M x 512] = A[M x 512] @ W[512 x 512] + bias ----------------
#define GBM 128
#define GBN 128
#define GBK 16

__global__ __launch_bounds__(256)
void gemm512(const float* __restrict__ A, const float* __restrict__ W,
             const float* __restrict__ bias, float* __restrict__ C) {
    __shared__ float As[GBK][GBM + 4];
    __shared__ float Bs[GBK][GBN + 4];
    int m0 = blockIdx.y * GBM;
    int n0 = blockIdx.x * GBN;
    int tid = threadIdx.x;
    int tn = tid & 15, tm = tid >> 4;
    float acc[8][8];
#pragma unroll
    for (int i = 0; i < 8; i++)
#pragma unroll
        for (int j = 0; j < 8; j++) acc[i][j] = 0.f;

    for (int k0 = 0; k0 < 512; k0 += GBK) {
#pragma unroll
        for (int l = 0; l < 2; l++) {
            int f = tid + l * 256;
            int row = f >> 2, ks = (f & 3) * 4;
            float4 a = *(const float4*)(A + (size_t)(m0 + row) * 512 + k0 + ks);
            As[ks + 0][row] = a.x;
            As[ks + 1][row] = a.y;
            As[ks + 2][row] = a.z;
            As[ks + 3][row] = a.w;
        }
#pragma unroll
        for (int l = 0; l < 2; l++) {
            int f = tid + l * 256;
            int row = f >> 5, ns = (f & 31) * 4;
            *(float4*)(&Bs[row][ns]) = *(const float4*)(W + (size_t)(k0 + row) * 512 + n0 + ns);
        }
        __syncthreads();
#pragma unroll
        for (int kk = 0; kk < GBK; kk++) {
            float a[8], b[8];
#pragma unroll
            for (int i = 0; i < 8; i++) a[i] = As[kk][tm * 8 + i];
#pragma unroll
            for (int j = 0; j < 8; j++) b[j] = Bs[kk][tn * 8 + j];
#pragma unroll
            for (int i = 0; i < 8; i++)
#pragma unroll
                for (int j = 0; j < 8; j++)
                    acc[i][j] = fmaf(a[i], b[j], acc[i][j]);
        }
        __syncthreads();
    }
#pragma unroll
    for (int i = 0; i < 8; i++) {
        int m = m0 + tm * 8 + i;
#pragma unroll
        for (int j = 0; j < 8; j++) {
            int n = n0 + tn * 8 + j;
            C[(size_t)m * 512 + n] = acc[i][j] + bias[n];
        }
    }
}

// ---------------- sampled QK^T -> M ----------------
__global__ __launch_bounds__(256)
void sample_m_kernel(const float* __restrict__ q, const float* __restrict__ k,
                     const int* __restrict__ idx, float* __restrict__ M) {
    int i = blockIdx.x;
    int b = blockIdx.y;
    __shared__ float kb[SK][DM + 4];
    __shared__ float qs[DM];
    __shared__ float dots[H_][SK];
    int tid = threadIdx.x;
    if (tid < 128) {
        *(float4*)(&qs[tid * 4]) = *(const float4*)(q + ((size_t)b * L + i) * DM + tid * 4);
    }
#pragma unroll
    for (int l = 0; l < 12; l++) {
        int f = tid + l * 256;
        int r = f >> 7, seg = (f & 127) * 4;
        int row = idx[i * SK + r];
        *(float4*)(&kb[r][seg]) = *(const float4*)(k + ((size_t)b * L + row) * DM + seg);
    }
    __syncthreads();
    if (tid < H_ * SK) {
        int h = tid / SK, j = tid % SK;
        float s = 0.f;
        const float* qp = qs + h * DH;
        const float* kp = &kb[j][h * DH];
#pragma unroll
        for (int d = 0; d < DH; d++) s = fmaf(qp[d], kp[d], s);
        dots[h][j] = s;
    }
    __syncthreads();
    if (tid < H_) {
        float mx = -1e30f, sm = 0.f;
#pragma unroll
        for (int j = 0; j < SK; j++) { float v = dots[tid][j]; mx = fmaxf(mx, v); sm += v; }
        M[((size_t)b * H_ + tid) * L + i] = mx - sm * (1.0f / L);
    }
}

// ---------------- top-24 per (b,h), low-index tie-break ----------------
__global__ __launch_bounds__(256)
void topk_kernel(const float* __restrict__ M, int* __restrict__ mtop) {
    int bh = blockIdx.x;
    __shared__ float vals[L];
    __shared__ float rv[4];
    __shared__ int ri[4];
    int tid = threadIdx.x;
    const float* Mr = M + (size_t)bh * L;
    for (int t = tid; t < L; t += 256) vals[t] = Mr[t];
    __syncthreads();
    for (int it = 0; it < NTOP; it++) {
        float bv = -1e30f; int bi = 0x7fffffff;
        for (int t = tid; t < L; t += 256) {
            float v = vals[t];
            if (v > bv || (v == bv && t < bi)) { bv = v; bi = t; }
        }
        for (int o = 32; o > 0; o >>= 1) {
            float ov = __shfl_down(bv, o, 64);
            int oi = __shfl_down(bi, o, 64);
            if (ov > bv || (ov == bv && oi < bi)) { bv = ov; bi = oi; }
        }
        int wid = tid >> 6, lane = tid & 63;
        if (lane == 0) { rv[wid] = bv; ri[wid] = bi; }
        __syncthreads();
        if (tid == 0) {
            float fbv = rv[0]; int fbi = ri[0];
            for (int wv = 1; wv < 4; wv++)
                if (rv[wv] > fbv || (rv[wv] == fbv && ri[wv] < fbi)) { fbv = rv[wv]; fbi = ri[wv]; }
            mtop[bh * NTOP + it] = fbi;
            vals[fbi] = -1e30f;
        }
        __syncthreads();
    }
}

// ---------------- padding cumsum ----------------
__global__ __launch_bounds__(256)
void padscan_kernel(const float* __restrict__ pad, float* __restrict__ denom) {
    int b = blockIdx.x;
    __shared__ float tot[256];
    int tid = threadIdx.x;
    const float* p = pad + (size_t)b * L;
    float loc[8];
    float s = 0.f;
#pragma unroll
    for (int u = 0; u < 8; u++) { s += p[tid * 8 + u]; loc[u] = s; }
    tot[tid] = s;
    __syncthreads();
    for (int off = 1; off < 256; off <<= 1) {
        float add = (tid >= off) ? tot[tid - off] : 0.f;
        __syncthreads();
        tot[tid] += add;
        __syncthreads();
    }
    float excl = tot[tid] - s;
#pragma unroll
    for (int u = 0; u < 8; u++) denom[(size_t)b * L + tid * 8 + u] = excl + loc[u];
}

// ---------------- cumulative average of V (3 passes) ----------------
__global__ __launch_bounds__(512)
void vavg1_kernel(const float* __restrict__ v, float* __restrict__ pre, float* __restrict__ csum) {
    int c = blockIdx.x, b = blockIdx.y, d = threadIdx.x;
    size_t base = ((size_t)b * L + c * 128) * DM + d;
    float acc = 0.f;
    for (int t = 0; t < 128; t++) {
        acc += v[base + (size_t)t * DM];
        pre[base + (size_t)t * DM] = acc;
    }
    csum[((size_t)b * 16 + c) * DM + d] = acc;
}

__global__ __launch_bounds__(512)
void vavg2_kernel(float* __restrict__ csum) {
    int b = blockIdx.x, d = threadIdx.x;
    float run = 0.f;
    for (int c = 0; c < 16; c++) {
        size_t o = ((size_t)b * 16 + c) * DM + d;
        float t = csum[o];
        csum[o] = run;
        run += t;
    }
}

__global__ __launch_bounds__(512)
void vavg3_kernel(float* __restrict__ pre, const float* __restrict__ csum,
                  const float* __restrict__ denom) {
    int c = blockIdx.x, b = blockIdx.y, d = threadIdx.x;
    float off = csum[((size_t)b * 16 + c) * DM + d];
    size_t base = ((size_t)b * L + c * 128) * DM + d;
    for (int t = 0; t < 128; t++) {
        float dn = denom[(size_t)b * L + c * 128 + t] + 1e-12f;
        pre[base + (size_t)t * DM] = (pre[base + (size_t)t * DM] + off) / dn;
    }
}

// ---------------- split-chunk sparse attention ----------------
// Block (c, bh): computes partial softmax/PV for all 24 selected queries over
// j in [c*CHUNK, (c+1)*CHUNK). Partials: m (max), s (expsum), acc[64].
__global__ __launch_bounds__(256)
void attn_chunk_kernel(const float* __restrict__ q, const float* __restrict__ k,
                       const float* __restrict__ v, const int* __restrict__ mtop,
                       const float* __restrict__ pad,
                       float* __restrict__ part_m, float* __restrict__ part_s,
                       float* __restrict__ part_acc) {
    int c = blockIdx.x, bh = blockIdx.y;
    int b = bh >> 3, h = bh & 7;
    int j0 = c * CHUNK;
    __shared__ float Ks[CHUNK][68];    // K tile, later reused as V tile
    __shared__ float Pst[CHUNK][28];   // P transposed: [j][u]
    __shared__ int   iq_s[24];
    __shared__ int   lim_s[24];
    __shared__ float scl_s[24];
    int tid = threadIdx.x;
    if (tid < 24) {
        int iq = mtop[bh * NTOP + tid];
        iq_s[tid] = iq;
        bool ok = pad[(size_t)b * L + iq] != 0.f;
        lim_s[tid] = ok ? iq : (L - 1);
        scl_s[tid] = ok ? 0.044194173824159216f : 0.f;  // 1/sqrt(512) or 0
    }
    // stage K chunk (coalesced: 16 threads x float4 per row)
#pragma unroll
    for (int l = 0; l < 8; l++) {
        int f = tid + l * 256;
        int row = f >> 4, seg = (f & 15) * 4;
        *(float4*)&Ks[row][seg] =
            *(const float4*)(k + ((size_t)b * L + j0 + row) * DM + h * DH + seg);
    }
    __syncthreads();

    int uslot = tid >> 3, jslot = tid & 7;   // 32 u-slots (24 active) x 8 j-slots
    if (uslot < 24) {
        // Q row in registers
        float4 qv[16];
        const float* qp = q + ((size_t)b * L + iq_s[uslot]) * DM + h * DH;
#pragma unroll
        for (int dd = 0; dd < 16; dd++) qv[dd] = ((const float4*)qp)[dd];
        int lim = lim_s[uslot];
        float sc = scl_s[uslot];
        float vals[16];
        float lmax = -1e30f;
#pragma unroll
        for (int i = 0; i < 16; i++) {
            int j = jslot + 8 * i;
            float s = 0.f;
#pragma unroll
            for (int dd = 0; dd < 16; dd++) {
                float4 kv = *(const float4*)&Ks[j][dd * 4];
                s = fmaf(qv[dd].x, kv.x, s);
                s = fmaf(qv[dd].y, kv.y, s);
                s = fmaf(qv[dd].z, kv.z, s);
                s = fmaf(qv[dd].w, kv.w, s);
            }
            float sv = (j0 + j <= lim) ? s * sc : -1e30f;
            vals[i] = sv;
            lmax = fmaxf(lmax, sv);
        }
        // chunk max over the 8 j-slot lanes (adjacent lanes, same wave)
        lmax = fmaxf(lmax, __shfl_xor(lmax, 1, 64));
        lmax = fmaxf(lmax, __shfl_xor(lmax, 2, 64));
        lmax = fmaxf(lmax, __shfl_xor(lmax, 4, 64));
        bool any = lmax > -1e29f;
        float lsum = 0.f;
#pragma unroll
        for (int i = 0; i < 16; i++) {
            float e = any ? __expf(vals[i] - lmax) : 0.f;
            Pst[jslot + 8 * i][uslot] = e;
            lsum += e;
        }
        lsum += __shfl_xor(lsum, 1, 64);
        lsum += __shfl_xor(lsum, 2, 64);
        lsum += __shfl_xor(lsum, 4, 64);
        if (jslot == 0) {
            part_m[(bh * NTOP + uslot) * NCH + c] = lmax;
            part_s[(bh * NTOP + uslot) * NCH + c] = lsum;
        }
    }
    __syncthreads();
    // stage V chunk into Ks
#pragma unroll
    for (int l = 0; l < 8; l++) {
        int f = tid + l * 256;
        int row = f >> 4, seg = (f & 15) * 4;
        *(float4*)&Ks[row][seg] =
            *(const float4*)(v + ((size_t)b * L + j0 + row) * DM + h * DH + seg);
    }
    __syncthreads();
    // PV: wave g owns u in [6g, 6g+5]; lane d accumulates over chunk
    int d = tid & 63, g = tid >> 6;
    float acc[6] = {0.f, 0.f, 0.f, 0.f, 0.f, 0.f};
    for (int j = 0; j < CHUNK; j++) {
        float vv = Ks[j][d];
        float2 p01 = *(float2*)&Pst[j][6 * g];
        float2 p23 = *(float2*)&Pst[j][6 * g + 2];
        float2 p45 = *(float2*)&Pst[j][6 * g + 4];
        acc[0] = fmaf(p01.x, vv, acc[0]);
        acc[1] = fmaf(p01.y, vv, acc[1]);
        acc[2] = fmaf(p23.x, vv, acc[2]);
        acc[3] = fmaf(p23.y, vv, acc[3]);
        acc[4] = fmaf(p45.x, vv, acc[4]);
        acc[5] = fmaf(p45.y, vv, acc[5]);
    }
#pragma unroll
    for (int up = 0; up < 6; up++) {
        int u = g * 6 + up;
        part_acc[((size_t)(bh * NTOP + u) * NCH + c) * 64 + d] = acc[up];
    }
}

// merge 16 chunk partials per (bh,u) and scatter into pre
__global__ __launch_bounds__(256)
void attn_merge_kernel(const float* __restrict__ part_m, const float* __restrict__ part_s,
                       const float* __restrict__ part_acc, const int* __restrict__ mtop,
                       float* __restrict__ pre) {
    int ug = blockIdx.x;            // 0..5
    int bh = blockIdx.y;
    int b = bh >> 3, h = bh & 7;
    int tid = threadIdx.x;
    int u = ug * 4 + (tid >> 6);    // 4 u per block
    int d = tid & 63;
    int base = (bh * NTOP + u) * NCH;
    float m = -1e30f;
#pragma unroll
    for (int c = 0; c < NCH; c++) m = fmaxf(m, part_m[base + c]);
    float s = 0.f, o = 0.f;
#pragma unroll
    for (int c = 0; c < NCH; c++) {
        float w = __expf(part_m[base + c] - m);
        s += part_s[base + c] * w;
        o = fmaf(part_acc[(size_t)(base + c) * 64 + d], w, o);
    }
    o /= s;
    int iq = mtop[bh * NTOP + u];
    pre[((size_t)b * L + iq) * DM + h * DH + d] = o;
}

extern "C" void kernel_launch(void* const* d_in, const int* in_sizes, int n_in,
                              void* d_out, int out_size, void* d_ws, size_t ws_size,
                              hipStream_t stream) {
    const float* queries = (const float*)d_in[0];
    const float* keys    = (const float*)d_in[1];
    const float* values  = (const float*)d_in[2];
    const float* pad     = (const float*)d_in[3];
    const float* Wq = (const float*)d_in[4];  const float* bq = (const float*)d_in[5];
    const float* Wk = (const float*)d_in[6];  const float* bk = (const float*)d_in[7];
    const float* Wv = (const float*)d_in[8];  const float* bv = (const float*)d_in[9];
    const float* Wf = (const float*)d_in[10]; const float* bf = (const float*)d_in[11];
    const float* qlnw = (const float*)d_in[12]; const float* qlnb = (const float*)d_in[13];
    const float* flnw = (const float*)d_in[14]; const float* flnb = (const float*)d_in[15];
    const int* idx = (const int*)d_in[16];

    float* ws = (float*)d_ws;
    const size_t NE = (size_t)B_ * L * DM;   // 8388608
    float* qb    = ws;
    float* kb    = ws + NE;
    float* vb    = ws + 2 * NE;
    float* pre   = ws + 3 * NE;
    float* Mbuf  = ws + 4 * NE;                      // 64*2048
    float* denom = Mbuf + (size_t)B_ * H_ * L;       // 8*2048
    float* csum  = denom + (size_t)B_ * L;           // 8*16*512
    int*   mtop  = (int*)(csum + (size_t)B_ * 16 * DM);
    float* tmp   = (float*)d_out;  // reuse output buffer as scratch

    // attention partials live in the (idle) d_out region: 1.62M floats = 6.5 MB
    float* part_m   = tmp;                     // 64*24*16
    float* part_s   = part_m + 64 * NTOP * NCH;
    float* part_acc = part_s + 64 * NTOP * NCH; // 64*24*16*64

    padscan_kernel<<<B_, 256, 0, stream>>>(pad, denom);
    ln_kernel<<<B_ * L, 256, 0, stream>>>(queries, qlnw, qlnb, tmp);
    dim3 gg(4, 128);
    gemm512<<<gg, 256, 0, stream>>>(tmp, Wq, bq, qb);   // tmp free after this
    gemm512<<<gg, 256, 0, stream>>>(keys, Wk, bk, kb);
    gemm512<<<gg, 256, 0, stream>>>(values, Wv, bv, vb);
    dim3 gm(L, B_);
    sample_m_kernel<<<gm, 256, 0, stream>>>(qb, kb, idx, Mbuf);
    topk_kernel<<<B_ * H_, 256, 0, stream>>>(Mbuf, mtop);
    dim3 gv(16, B_);
    vavg1_kernel<<<gv, 512, 0, stream>>>(vb, pre, csum);
    vavg2_kernel<<<B_, 512, 0, stream>>>(csum);
    vavg3_kernel<<<gv, 512, 0, stream>>>(pre, csum, denom);
    dim3 gc(NCH, 64);
    attn_chunk_kernel<<<gc, 256, 0, stream>>>(qb, kb, vb, mtop, pad,
                                              part_m, part_s, part_acc);
    dim3 gmg(6, 64);
    attn_merge_kernel<<<gmg, 256, 0, stream>>>(part_m, part_s, part_acc, mtop, pre);
    gemm512<<<gg, 256, 0, stream>>>(pre, Wf, bf, tmp);
    ln_kernel<<<B_ * L, 256, 0, stream>>>(tmp, flnw, flnb, (float*)d_out);
}

// Round 3
// 378.737 us; speedup vs baseline: 2.1945x; 1.7076x over previous
//
#include <hip/hip_runtime.h>
#include <math.h>

#define L 2048
#define DM 512
#define B_ 8
#define H_ 8
#define DH 64
#define SK 24
#define NTOP 24
#define CHUNK 128
#define NCH (L / CHUNK)   // 16

typedef __attribute__((ext_vector_type(8))) short short8;
typedef __attribute__((ext_vector_type(8))) __bf16 bf16x8;
typedef __attribute__((ext_vector_type(4))) float f32x4;

__device__ inline unsigned short f2bf(float x) {
    unsigned u = __float_as_uint(x);
    unsigned r = (u + 0x7FFFu + ((u >> 16) & 1u)) >> 16;
    return (unsigned short)r;
}
__device__ inline float bf2f(unsigned short h) {
    return __uint_as_float(((unsigned)h) << 16);
}

__device__ inline f32x4 MFMA_BF16(short8 a, short8 b, f32x4 c) {
    return __builtin_amdgcn_mfma_f32_16x16x32_bf16(
        __builtin_bit_cast(bf16x8, a), __builtin_bit_cast(bf16x8, b), c, 0, 0, 0);
}

// ---------------- reduce helpers ----------------
__device__ inline float waveReduceSum(float v) {
    for (int o = 32; o > 0; o >>= 1) v += __shfl_down(v, o, 64);
    return v;
}
__device__ inline float waveReduceMax(float v) {
    for (int o = 32; o > 0; o >>= 1) v = fmaxf(v, __shfl_down(v, o, 64));
    return v;
}

// ---------------- LayerNorm (row-wise, 512 cols) f32 out ----------------
__global__ __launch_bounds__(256)
void ln_kernel(const float* __restrict__ x, const float* __restrict__ w,
               const float* __restrict__ bvec, float* __restrict__ out) {
    int row = blockIdx.x;
    const float* xr = x + (size_t)row * DM;
    float* orow = out + (size_t)row * DM;
    int tid = threadIdx.x;
    float2 v = *(const float2*)(xr + tid * 2);
    float s = v.x + v.y;
    float sq = v.x * v.x + v.y * v.y;
    __shared__ float red[8];
    float ws = waveReduceSum(s);
    float wq = waveReduceSum(sq);
    int wid = tid >> 6, lane = tid & 63;
    if (lane == 0) { red[wid] = ws; red[4 + wid] = wq; }
    __syncthreads();
    float tot = red[0] + red[1] + red[2] + red[3];
    float totq = red[4] + red[5] + red[6] + red[7];
    float mean = tot * (1.0f / DM);
    float var = totq * (1.0f / DM) - mean * mean;
    float inv = rsqrtf(var + 1e-8f);
    float w0 = w[tid * 2], w1 = w[tid * 2 + 1];
    float b0 = bvec[tid * 2], b1 = bvec[tid * 2 + 1];
    float2 o;
    o.x = w0 * (v.x - mean) * inv + b0;
    o.y = w1 * (v.y - mean) * inv + b1;
    *(float2*)(orow + tid * 2) = o;
}

// ---------------- LayerNorm with bf16 hi/lo split output ----------------
__global__ __launch_bounds__(256)
void ln_split_kernel(const float* __restrict__ x, const float* __restrict__ w,
                     const float* __restrict__ bvec,
                     unsigned short* __restrict__ oh, unsigned short* __restrict__ ol) {
    int row = blockIdx.x;
    const float* xr = x + (size_t)row * DM;
    int tid = threadIdx.x;
    float2 v = *(const float2*)(xr + tid * 2);
    float s = v.x + v.y;
    float sq = v.x * v.x + v.y * v.y;
    __shared__ float red[8];
    float ws = waveReduceSum(s);
    float wq = waveReduceSum(sq);
    int wid = tid >> 6, lane = tid & 63;
    if (lane == 0) { red[wid] = ws; red[4 + wid] = wq; }
    __syncthreads();
    float tot = red[0] + red[1] + red[2] + red[3];
    float totq = red[4] + red[5] + red[6] + red[7];
    float mean = tot * (1.0f / DM);
    float var = totq * (1.0f / DM) - mean * mean;
    float inv = rsqrtf(var + 1e-8f);
    float w0 = w[tid * 2], w1 = w[tid * 2 + 1];
    float b0 = bvec[tid * 2], b1 = bvec[tid * 2 + 1];
    float o0 = w0 * (v.x - mean) * inv + b0;
    float o1 = w1 * (v.y - mean) * inv + b1;
    ushort2 hh, ll;
    hh.x = f2bf(o0); ll.x = f2bf(o0 - bf2f(hh.x));
    hh.y = f2bf(o1); ll.y = f2bf(o1 - bf2f(hh.y));
    *(ushort2*)(oh + (size_t)row * DM + tid * 2) = hh;
    *(ushort2*)(ol + (size_t)row * DM + tid * 2) = ll;
}

// ---------------- hi/lo split (full) ----------------
__global__ __launch_bounds__(256)
void split2_kernel(const float* __restrict__ x, unsigned short* __restrict__ hi,
                   unsigned short* __restrict__ lo) {
    int i = blockIdx.x * 256 + threadIdx.x;   // one float4 each
    float4 v = *(const float4*)(x + (size_t)i * 4);
    ushort4 h, l;
    h.x = f2bf(v.x); l.x = f2bf(v.x - bf2f(h.x));
    h.y = f2bf(v.y); l.y = f2bf(v.y - bf2f(h.y));
    h.z = f2bf(v.z); l.z = f2bf(v.z - bf2f(h.z));
    h.w = f2bf(v.w); l.w = f2bf(v.w - bf2f(h.w));
    *(ushort4*)(hi + (size_t)i * 4) = h;
    *(ushort4*)(lo + (size_t)i * 4) = l;
}

// ---------------- hi-only split ----------------
__global__ __launch_bounds__(256)
void split1_kernel(const float* __restrict__ x, unsigned short* __restrict__ hi) {
    int i = blockIdx.x * 256 + threadIdx.x;
    float4 v = *(const float4*)(x + (size_t)i * 4);
    ushort4 h;
    h.x = f2bf(v.x); h.y = f2bf(v.y); h.z = f2bf(v.z); h.w = f2bf(v.w);
    *(ushort4*)(hi + (size_t)i * 4) = h;
}

// ---------------- W transpose + hi/lo split: Wt[n][k] = W[k][n] ----------------
__global__ __launch_bounds__(256)
void wsplit_kernel(const float* __restrict__ W, unsigned short* __restrict__ th,
                   unsigned short* __restrict__ tl) {
    __shared__ float ts[32][33];
    int k0 = blockIdx.y * 32, n0 = blockIdx.x * 32;
    int t = threadIdx.x;
    int r = t >> 3, c = (t & 7) * 4;
    float4 v = *(const float4*)(W + (size_t)(k0 + r) * 512 + n0 + c);
    ts[r][c] = v.x; ts[r][c + 1] = v.y; ts[r][c + 2] = v.z; ts[r][c + 3] = v.w;
    __syncthreads();
    float a0 = ts[c + 0][r], a1 = ts[c + 1][r], a2 = ts[c + 2][r], a3 = ts[c + 3][r];
    ushort4 h, l;
    h.x = f2bf(a0); l.x = f2bf(a0 - bf2f(h.x));
    h.y = f2bf(a1); l.y = f2bf(a1 - bf2f(h.y));
    h.z = f2bf(a2); l.z = f2bf(a2 - bf2f(h.z));
    h.w = f2bf(a3); l.w = f2bf(a3 - bf2f(h.w));
    *(ushort4*)(th + (size_t)(n0 + r) * 512 + k0 + c) = h;
    *(ushort4*)(tl + (size_t)(n0 + r) * 512 + k0 + c) = l;
}

// ---------------- MFMA split GEMM: C[16384 x 512] = A @ W + bias ----------------
// A given as hi(/lo) bf16 row-major [M][512]; W given transposed+split [n][k].
// TERMS==3: A_h*W_h + A_h*W_l + A_l*W_h ; TERMS==2: A_h*W_h + A_h*W_l.
template<int TERMS>
__global__ __launch_bounds__(256, 2)
void gemm_mfma(const unsigned short* __restrict__ Ah, const unsigned short* __restrict__ Al,
               const unsigned short* __restrict__ Bh, const unsigned short* __restrict__ Bl,
               const float* __restrict__ bias, float* __restrict__ C) {
    __shared__ __align__(16) unsigned short smem[20480];  // 40KB
    unsigned short* sAh = smem;              // [128][40]
    unsigned short* sAl = smem + 5120;
    unsigned short* sBh = smem + 10240;
    unsigned short* sBl = smem + 15360;

    // XCD-aware swizzle: each XCD gets a contiguous 16-row M band
    int orig = blockIdx.x + 4 * blockIdx.y;          // 512 blocks
    int j = (orig & 7) * 64 + (orig >> 3);
    int n0 = (j & 3) * 128, m0 = (j >> 2) * 128;

    int tid = threadIdx.x;
    int lane = tid & 63, wv = tid >> 6;
    int wr = wv >> 1, wc = wv & 1;
    int lrow = lane & 15;
    int kofs = (lane >> 4) * 8;

    int f0 = tid, f1 = tid + 256;
    int row0 = f0 >> 2, c0 = (f0 & 3) * 8;
    int row1 = f1 >> 2, c1 = (f1 & 3) * 8;

    f32x4 acc[4][4];
#pragma unroll
    for (int mf = 0; mf < 4; mf++)
#pragma unroll
        for (int nf = 0; nf < 4; nf++) acc[mf][nf] = (f32x4){0.f, 0.f, 0.f, 0.f};

    short8 rAh0, rAh1, rAl0, rAl1, rBh0, rBh1, rBl0, rBl1;

    auto LOAD = [&](int kt) {
        int k0 = kt * 32;
        rAh0 = *(const short8*)(Ah + (size_t)(m0 + row0) * 512 + k0 + c0);
        rAh1 = *(const short8*)(Ah + (size_t)(m0 + row1) * 512 + k0 + c1);
        if (TERMS == 3) {
            rAl0 = *(const short8*)(Al + (size_t)(m0 + row0) * 512 + k0 + c0);
            rAl1 = *(const short8*)(Al + (size_t)(m0 + row1) * 512 + k0 + c1);
        }
        rBh0 = *(const short8*)(Bh + (size_t)(n0 + row0) * 512 + k0 + c0);
        rBh1 = *(const short8*)(Bh + (size_t)(n0 + row1) * 512 + k0 + c1);
        rBl0 = *(const short8*)(Bl + (size_t)(n0 + row0) * 512 + k0 + c0);
        rBl1 = *(const short8*)(Bl + (size_t)(n0 + row1) * 512 + k0 + c1);
    };
    auto STORE = [&]() {
        *(short8*)&sAh[row0 * 40 + c0] = rAh0;
        *(short8*)&sAh[row1 * 40 + c1] = rAh1;
        if (TERMS == 3) {
            *(short8*)&sAl[row0 * 40 + c0] = rAl0;
            *(short8*)&sAl[row1 * 40 + c1] = rAl1;
        }
        *(short8*)&sBh[row0 * 40 + c0] = rBh0;
        *(short8*)&sBh[row1 * 40 + c1] = rBh1;
        *(short8*)&sBl[row0 * 40 + c0] = rBl0;
        *(short8*)&sBl[row1 * 40 + c1] = rBl1;
    };

    int abase = (wr * 64 + lrow) * 40 + kofs;
    int bbase = (wc * 64 + lrow) * 40 + kofs;

    LOAD(0);
    for (int kt = 0; kt < 16; kt++) {
        STORE();
        __syncthreads();
        if (kt < 15) LOAD(kt + 1);
        short8 ah[4], al[4], bh[4], bl[4];
#pragma unroll
        for (int mf = 0; mf < 4; mf++) {
            ah[mf] = *(const short8*)&sAh[abase + mf * 640];
            if (TERMS == 3) al[mf] = *(const short8*)&sAl[abase + mf * 640];
        }
#pragma unroll
        for (int nf = 0; nf < 4; nf++) {
            bh[nf] = *(const short8*)&sBh[bbase + nf * 640];
            bl[nf] = *(const short8*)&sBl[bbase + nf * 640];
        }
#pragma unroll
        for (int mf = 0; mf < 4; mf++)
#pragma unroll
            for (int nf = 0; nf < 4; nf++) {
                acc[mf][nf] = MFMA_BF16(ah[mf], bh[nf], acc[mf][nf]);
                acc[mf][nf] = MFMA_BF16(ah[mf], bl[nf], acc[mf][nf]);
                if (TERMS == 3) acc[mf][nf] = MFMA_BF16(al[mf], bh[nf], acc[mf][nf]);
            }
        __syncthreads();
    }

    int crow0 = m0 + wr * 64 + (lane >> 4) * 4;
    int ccol0 = n0 + wc * 64 + lrow;
    float bb[4];
#pragma unroll
    for (int nf = 0; nf < 4; nf++) bb[nf] = bias[ccol0 + nf * 16];
#pragma unroll
    for (int mf = 0; mf < 4; mf++)
#pragma unroll
        for (int nf = 0; nf < 4; nf++)
#pragma unroll
            for (int r = 0; r < 4; r++)
                C[(size_t)(crow0 + mf * 16 + r) * 512 + ccol0 + nf * 16] =
                    acc[mf][nf][r] + bb[nf];
}

// ---------------- sampled QK^T -> M ----------------
__global__ __launch_bounds__(256)
void sample_m_kernel(const float* __restrict__ q, const float* __restrict__ k,
                     const int* __restrict__ idx, float* __restrict__ M) {
    int i = blockIdx.x;
    int b = blockIdx.y;
    __shared__ float kb[SK][DM + 4];
    __shared__ float qs[DM];
    __shared__ float dots[H_][SK];
    int tid = threadIdx.x;
    if (tid < 128) {
        *(float4*)(&qs[tid * 4]) = *(const float4*)(q + ((size_t)b * L + i) * DM + tid * 4);
    }
#pragma unroll
    for (int l = 0; l < 12; l++) {
        int f = tid + l * 256;
        int r = f >> 7, seg = (f & 127) * 4;
        int row = idx[i * SK + r];
        *(float4*)(&kb[r][seg]) = *(const float4*)(k + ((size_t)b * L + row) * DM + seg);
    }
    __syncthreads();
    if (tid < H_ * SK) {
        int h = tid / SK, j = tid % SK;
        float s = 0.f;
        const float* qp = qs + h * DH;
        const float* kp = &kb[j][h * DH];
#pragma unroll
        for (int d = 0; d < DH; d++) s = fmaf(qp[d], kp[d], s);
        dots[h][j] = s;
    }
    __syncthreads();
    if (tid < H_) {
        float mx = -1e30f, sm = 0.f;
#pragma unroll
        for (int j = 0; j < SK; j++) { float v = dots[tid][j]; mx = fmaxf(mx, v); sm += v; }
        M[((size_t)b * H_ + tid) * L + i] = mx - sm * (1.0f / L);
    }
}

// ---------------- top-24 per (b,h), low-index tie-break ----------------
__global__ __launch_bounds__(256)
void topk_kernel(const float* __restrict__ M, int* __restrict__ mtop) {
    int bh = blockIdx.x;
    __shared__ float vals[L];
    __shared__ float rv[4];
    __shared__ int ri[4];
    int tid = threadIdx.x;
    const float* Mr = M + (size_t)bh * L;
    for (int t = tid; t < L; t += 256) vals[t] = Mr[t];
    __syncthreads();
    for (int it = 0; it < NTOP; it++) {
        float bv = -1e30f; int bi = 0x7fffffff;
        for (int t = tid; t < L; t += 256) {
            float v = vals[t];
            if (v > bv || (v == bv && t < bi)) { bv = v; bi = t; }
        }
        for (int o = 32; o > 0; o >>= 1) {
            float ov = __shfl_down(bv, o, 64);
            int oi = __shfl_down(bi, o, 64);
            if (ov > bv || (ov == bv && oi < bi)) { bv = ov; bi = oi; }
        }
        int wid = tid >> 6, lane = tid & 63;
        if (lane == 0) { rv[wid] = bv; ri[wid] = bi; }
        __syncthreads();
        if (tid == 0) {
            float fbv = rv[0]; int fbi = ri[0];
            for (int wv = 1; wv < 4; wv++)
                if (rv[wv] > fbv || (rv[wv] == fbv && ri[wv] < fbi)) { fbv = rv[wv]; fbi = ri[wv]; }
            mtop[bh * NTOP + it] = fbi;
            vals[fbi] = -1e30f;
        }
        __syncthreads();
    }
}

// ---------------- padding cumsum ----------------
__global__ __launch_bounds__(256)
void padscan_kernel(const float* __restrict__ pad, float* __restrict__ denom) {
    int b = blockIdx.x;
    __shared__ float tot[256];
    int tid = threadIdx.x;
    const float* p = pad + (size_t)b * L;
    float loc[8];
    float s = 0.f;
#pragma unroll
    for (int u = 0; u < 8; u++) { s += p[tid * 8 + u]; loc[u] = s; }
    tot[tid] = s;
    __syncthreads();
    for (int off = 1; off < 256; off <<= 1) {
        float add = (tid >= off) ? tot[tid - off] : 0.f;
        __syncthreads();
        tot[tid] += add;
        __syncthreads();
    }
    float excl = tot[tid] - s;
#pragma unroll
    for (int u = 0; u < 8; u++) denom[(size_t)b * L + tid * 8 + u] = excl + loc[u];
}

// ---------------- cumulative average of V (3 passes) ----------------
__global__ __launch_bounds__(512)
void vavg1_kernel(const float* __restrict__ v, float* __restrict__ pre, float* __restrict__ csum) {
    int c = blockIdx.x, b = blockIdx.y, d = threadIdx.x;
    size_t base = ((size_t)b * L + c * 128) * DM + d;
    float acc = 0.f;
    for (int t = 0; t < 128; t++) {
        acc += v[base + (size_t)t * DM];
        pre[base + (size_t)t * DM] = acc;
    }
    csum[((size_t)b * 16 + c) * DM + d] = acc;
}

__global__ __launch_bounds__(512)
void vavg2_kernel(float* __restrict__ csum) {
    int b = blockIdx.x, d = threadIdx.x;
    float run = 0.f;
    for (int c = 0; c < 16; c++) {
        size_t o = ((size_t)b * 16 + c) * DM + d;
        float t = csum[o];
        csum[o] = run;
        run += t;
    }
}

__global__ __launch_bounds__(512)
void vavg3_kernel(float* __restrict__ pre, const float* __restrict__ csum,
                  const float* __restrict__ denom) {
    int c = blockIdx.x, b = blockIdx.y, d = threadIdx.x;
    float off = csum[((size_t)b * 16 + c) * DM + d];
    size_t base = ((size_t)b * L + c * 128) * DM + d;
    for (int t = 0; t < 128; t++) {
        float dn = denom[(size_t)b * L + c * 128 + t] + 1e-12f;
        pre[base + (size_t)t * DM] = (pre[base + (size_t)t * DM] + off) / dn;
    }
}

// ---------------- split-chunk sparse attention ----------------
__global__ __launch_bounds__(256)
void attn_chunk_kernel(const float* __restrict__ q, const float* __restrict__ k,
                       const float* __restrict__ v, const int* __restrict__ mtop,
                       const float* __restrict__ pad,
                       float* __restrict__ part_m, float* __restrict__ part_s,
                       float* __restrict__ part_acc) {
    int c = blockIdx.x, bh = blockIdx.y;
    int b = bh >> 3, h = bh & 7;
    int j0 = c * CHUNK;
    __shared__ float Ks[CHUNK][68];
    __shared__ float Pst[CHUNK][28];
    __shared__ int   iq_s[24];
    __shared__ int   lim_s[24];
    __shared__ float scl_s[24];
    int tid = threadIdx.x;
    if (tid < 24) {
        int iq = mtop[bh * NTOP + tid];
        iq_s[tid] = iq;
        bool ok = pad[(size_t)b * L + iq] != 0.f;
        lim_s[tid] = ok ? iq : (L - 1);
        scl_s[tid] = ok ? 0.044194173824159216f : 0.f;
    }
#pragma unroll
    for (int l = 0; l < 8; l++) {
        int f = tid + l * 256;
        int row = f >> 4, seg = (f & 15) * 4;
        *(float4*)&Ks[row][seg] =
            *(const float4*)(k + ((size_t)b * L + j0 + row) * DM + h * DH + seg);
    }
    __syncthreads();

    int uslot = tid >> 3, jslot = tid & 7;
    if (uslot < 24) {
        float4 qv[16];
        const float* qp = q + ((size_t)b * L + iq_s[uslot]) * DM + h * DH;
#pragma unroll
        for (int dd = 0; dd < 16; dd++) qv[dd] = ((const float4*)qp)[dd];
        int lim = lim_s[uslot];
        float sc = scl_s[uslot];
        float vals[16];
        float lmax = -1e30f;
#pragma unroll
        for (int i = 0; i < 16; i++) {
            int j = jslot + 8 * i;
            float s = 0.f;
#pragma unroll
            for (int dd = 0; dd < 16; dd++) {
                float4 kv = *(const float4*)&Ks[j][dd * 4];
                s = fmaf(qv[dd].x, kv.x, s);
                s = fmaf(qv[dd].y, kv.y, s);
                s = fmaf(qv[dd].z, kv.z, s);
                s = fmaf(qv[dd].w, kv.w, s);
            }
            float sv = (j0 + j <= lim) ? s * sc : -1e30f;
            vals[i] = sv;
            lmax = fmaxf(lmax, sv);
        }
        lmax = fmaxf(lmax, __shfl_xor(lmax, 1, 64));
        lmax = fmaxf(lmax, __shfl_xor(lmax, 2, 64));
        lmax = fmaxf(lmax, __shfl_xor(lmax, 4, 64));
        bool any = lmax > -1e29f;
        float lsum = 0.f;
#pragma unroll
        for (int i = 0; i < 16; i++) {
            float e = any ? __expf(vals[i] - lmax) : 0.f;
            Pst[jslot + 8 * i][uslot] = e;
            lsum += e;
        }
        lsum += __shfl_xor(lsum, 1, 64);
        lsum += __shfl_xor(lsum, 2, 64);
        lsum += __shfl_xor(lsum, 4, 64);
        if (jslot == 0) {
            part_m[(bh * NTOP + uslot) * NCH + c] = lmax;
            part_s[(bh * NTOP + uslot) * NCH + c] = lsum;
        }
    }
    __syncthreads();
#pragma unroll
    for (int l = 0; l < 8; l++) {
        int f = tid + l * 256;
        int row = f >> 4, seg = (f & 15) * 4;
        *(float4*)&Ks[row][seg] =
            *(const float4*)(v + ((size_t)b * L + j0 + row) * DM + h * DH + seg);
    }
    __syncthreads();
    int d = tid & 63, g = tid >> 6;
    float acc[6] = {0.f, 0.f, 0.f, 0.f, 0.f, 0.f};
    for (int j = 0; j < CHUNK; j++) {
        float vv = Ks[j][d];
        float2 p01 = *(float2*)&Pst[j][6 * g];
        float2 p23 = *(float2*)&Pst[j][6 * g + 2];
        float2 p45 = *(float2*)&Pst[j][6 * g + 4];
        acc[0] = fmaf(p01.x, vv, acc[0]);
        acc[1] = fmaf(p01.y, vv, acc[1]);
        acc[2] = fmaf(p23.x, vv, acc[2]);
        acc[3] = fmaf(p23.y, vv, acc[3]);
        acc[4] = fmaf(p45.x, vv, acc[4]);
        acc[5] = fmaf(p45.y, vv, acc[5]);
    }
#pragma unroll
    for (int up = 0; up < 6; up++) {
        int u = g * 6 + up;
        part_acc[((size_t)(bh * NTOP + u) * NCH + c) * 64 + d] = acc[up];
    }
}

__global__ __launch_bounds__(256)
void attn_merge_kernel(const float* __restrict__ part_m, const float* __restrict__ part_s,
                       const float* __restrict__ part_acc, const int* __restrict__ mtop,
                       float* __restrict__ pre) {
    int ug = blockIdx.x;
    int bh = blockIdx.y;
    int b = bh >> 3, h = bh & 7;
    int tid = threadIdx.x;
    int u = ug * 4 + (tid >> 6);
    int d = tid & 63;
    int base = (bh * NTOP + u) * NCH;
    float m = -1e30f;
#pragma unroll
    for (int c = 0; c < NCH; c++) m = fmaxf(m, part_m[base + c]);
    float s = 0.f, o = 0.f;
#pragma unroll
    for (int c = 0; c < NCH; c++) {
        float w = __expf(part_m[base + c] - m);
        s += part_s[base + c] * w;
        o = fmaf(part_acc[(size_t)(base + c) * 64 + d], w, o);
    }
    o /= s;
    int iq = mtop[bh * NTOP + u];
    pre[((size_t)b * L + iq) * DM + h * DH + d] = o;
}

extern "C" void kernel_launch(void* const* d_in, const int* in_sizes, int n_in,
                              void* d_out, int out_size, void* d_ws, size_t ws_size,
                              hipStream_t stream) {
    const float* queries = (const float*)d_in[0];
    const float* keys    = (const float*)d_in[1];
    const float* values  = (const float*)d_in[2];
    const float* pad     = (const float*)d_in[3];
    const float* Wq = (const float*)d_in[4];  const float* bq = (const float*)d_in[5];
    const float* Wk = (const float*)d_in[6];  const float* bk = (const float*)d_in[7];
    const float* Wv = (const float*)d_in[8];  const float* bv = (const float*)d_in[9];
    const float* Wf = (const float*)d_in[10]; const float* bfv = (const float*)d_in[11];
    const float* qlnw = (const float*)d_in[12]; const float* qlnb = (const float*)d_in[13];
    const float* flnw = (const float*)d_in[14]; const float* flnb = (const float*)d_in[15];
    const int* idx = (const int*)d_in[16];

    float* ws = (float*)d_ws;
    const size_t NE = (size_t)B_ * L * DM;   // 8388608
    float* qb    = ws;
    float* kb    = ws + NE;
    float* vb    = ws + 2 * NE;
    float* pre   = ws + 3 * NE;
    float* Mbuf  = ws + 4 * NE;                      // 64*2048
    float* denom = Mbuf + (size_t)B_ * H_ * L;       // 8*2048
    float* csum  = denom + (size_t)B_ * L;           // 8*16*512
    int*   mtop  = (int*)(csum + (size_t)B_ * 16 * DM);
    unsigned short* bfr = (unsigned short*)(mtop + 2048);
    unsigned short* keys_h = bfr;
    unsigned short* keys_l = bfr + NE;
    unsigned short* vals_h = bfr + 2 * NE;
    unsigned short* wts    = bfr + 3 * NE;
    unsigned short* wq_h = wts;              unsigned short* wq_l = wts + 262144;
    unsigned short* wk_h = wts + 2 * 262144; unsigned short* wk_l = wts + 3 * 262144;
    unsigned short* wv_h = wts + 4 * 262144; unsigned short* wv_l = wts + 5 * 262144;
    unsigned short* wf_h = wts + 6 * 262144; unsigned short* wf_l = wts + 7 * 262144;
    unsigned short* pre_h = keys_h;          // alias: keys dead after k-GEMM

    float* tmp = (float*)d_out;
    unsigned short* lnq_h = (unsigned short*)d_out;   // d_out as bf16 scratch
    unsigned short* lnq_l = lnq_h + NE;
    float* part_m   = tmp;                            // later: attn partials
    float* part_s   = part_m + 64 * NTOP * NCH;
    float* part_acc = part_s + 64 * NTOP * NCH;

    padscan_kernel<<<B_, 256, 0, stream>>>(pad, denom);
    ln_split_kernel<<<B_ * L, 256, 0, stream>>>(queries, qlnw, qlnb, lnq_h, lnq_l);
    split2_kernel<<<NE / 1024, 256, 0, stream>>>(keys, keys_h, keys_l);
    split1_kernel<<<NE / 1024, 256, 0, stream>>>(values, vals_h);
    dim3 gw(16, 16);
    wsplit_kernel<<<gw, 256, 0, stream>>>(Wq, wq_h, wq_l);
    wsplit_kernel<<<gw, 256, 0, stream>>>(Wk, wk_h, wk_l);
    wsplit_kernel<<<gw, 256, 0, stream>>>(Wv, wv_h, wv_l);
    wsplit_kernel<<<gw, 256, 0, stream>>>(Wf, wf_h, wf_l);

    dim3 gg(4, 128);
    gemm_mfma<3><<<gg, 256, 0, stream>>>(lnq_h, lnq_l, wq_h, wq_l, bq, qb);
    gemm_mfma<3><<<gg, 256, 0, stream>>>(keys_h, keys_l, wk_h, wk_l, bk, kb);
    gemm_mfma<2><<<gg, 256, 0, stream>>>(vals_h, nullptr, wv_h, wv_l, bv, vb);

    dim3 gm(L, B_);
    sample_m_kernel<<<gm, 256, 0, stream>>>(qb, kb, idx, Mbuf);
    topk_kernel<<<B_ * H_, 256, 0, stream>>>(Mbuf, mtop);
    dim3 gv(16, B_);
    vavg1_kernel<<<gv, 512, 0, stream>>>(vb, pre, csum);
    vavg2_kernel<<<B_, 512, 0, stream>>>(csum);
    vavg3_kernel<<<gv, 512, 0, stream>>>(pre, csum, denom);
    dim3 gc(NCH, 64);
    attn_chunk_kernel<<<gc, 256, 0, stream>>>(qb, kb, vb, mtop, pad,
                                              part_m, part_s, part_acc);
    dim3 gmg(6, 64);
    attn_merge_kernel<<<gmg, 256, 0, stream>>>(part_m, part_s, part_acc, mtop, pre);
    split1_kernel<<<NE / 1024, 256, 0, stream>>>(pre, pre_h);
    gemm_mfma<2><<<gg, 256, 0, stream>>>(pre_h, nullptr, wf_h, wf_l, bfv, (float*)d_out);
    ln_kernel<<<B_ * L, 256, 0, stream>>>((float*)d_out, flnw, flnb, (float*)d_out);
}

// Round 4
// 357.951 us; speedup vs baseline: 2.3219x; 1.0581x over previous
//
#include <hip/hip_runtime.h>
#include <math.h>

#define L 2048
#define DM 512
#define B_ 8
#define H_ 8
#define DH 64
#define SK 24
#define NTOP 24
#define CHUNK 128
#define NCH (L / CHUNK)   // 16

typedef __attribute__((ext_vector_type(8))) short short8;
typedef __attribute__((ext_vector_type(8))) __bf16 bf16x8;
typedef __attribute__((ext_vector_type(4))) float f32x4;

__device__ inline unsigned short f2bf(float x) {
    unsigned u = __float_as_uint(x);
    unsigned r = (u + 0x7FFFu + ((u >> 16) & 1u)) >> 16;
    return (unsigned short)r;
}
__device__ inline float bf2f(unsigned short h) {
    return __uint_as_float(((unsigned)h) << 16);
}

__device__ inline f32x4 MFMA_BF16(short8 a, short8 b, f32x4 c) {
    return __builtin_amdgcn_mfma_f32_16x16x32_bf16(
        __builtin_bit_cast(bf16x8, a), __builtin_bit_cast(bf16x8, b), c, 0, 0, 0);
}

// ---------------- reduce helpers ----------------
__device__ inline float waveReduceSum(float v) {
    for (int o = 32; o > 0; o >>= 1) v += __shfl_down(v, o, 64);
    return v;
}
__device__ inline float waveReduceMax(float v) {
    for (int o = 32; o > 0; o >>= 1) v = fmaxf(v, __shfl_down(v, o, 64));
    return v;
}

// ---------------- LayerNorm (row-wise, 512 cols) f32 out ----------------
__global__ __launch_bounds__(256)
void ln_kernel(const float* __restrict__ x, const float* __restrict__ w,
               const float* __restrict__ bvec, float* __restrict__ out) {
    int row = blockIdx.x;
    const float* xr = x + (size_t)row * DM;
    float* orow = out + (size_t)row * DM;
    int tid = threadIdx.x;
    float2 v = *(const float2*)(xr + tid * 2);
    float s = v.x + v.y;
    float sq = v.x * v.x + v.y * v.y;
    __shared__ float red[8];
    float ws = waveReduceSum(s);
    float wq = waveReduceSum(sq);
    int wid = tid >> 6, lane = tid & 63;
    if (lane == 0) { red[wid] = ws; red[4 + wid] = wq; }
    __syncthreads();
    float tot = red[0] + red[1] + red[2] + red[3];
    float totq = red[4] + red[5] + red[6] + red[7];
    float mean = tot * (1.0f / DM);
    float var = totq * (1.0f / DM) - mean * mean;
    float inv = rsqrtf(var + 1e-8f);
    float w0 = w[tid * 2], w1 = w[tid * 2 + 1];
    float b0 = bvec[tid * 2], b1 = bvec[tid * 2 + 1];
    float2 o;
    o.x = w0 * (v.x - mean) * inv + b0;
    o.y = w1 * (v.y - mean) * inv + b1;
    *(float2*)(orow + tid * 2) = o;
}

// ---------------- LayerNorm with bf16 hi/lo split output ----------------
__global__ __launch_bounds__(256)
void ln_split_kernel(const float* __restrict__ x, const float* __restrict__ w,
                     const float* __restrict__ bvec,
                     unsigned short* __restrict__ oh, unsigned short* __restrict__ ol) {
    int row = blockIdx.x;
    const float* xr = x + (size_t)row * DM;
    int tid = threadIdx.x;
    float2 v = *(const float2*)(xr + tid * 2);
    float s = v.x + v.y;
    float sq = v.x * v.x + v.y * v.y;
    __shared__ float red[8];
    float ws = waveReduceSum(s);
    float wq = waveReduceSum(sq);
    int wid = tid >> 6, lane = tid & 63;
    if (lane == 0) { red[wid] = ws; red[4 + wid] = wq; }
    __syncthreads();
    float tot = red[0] + red[1] + red[2] + red[3];
    float totq = red[4] + red[5] + red[6] + red[7];
    float mean = tot * (1.0f / DM);
    float var = totq * (1.0f / DM) - mean * mean;
    float inv = rsqrtf(var + 1e-8f);
    float w0 = w[tid * 2], w1 = w[tid * 2 + 1];
    float b0 = bvec[tid * 2], b1 = bvec[tid * 2 + 1];
    float o0 = w0 * (v.x - mean) * inv + b0;
    float o1 = w1 * (v.y - mean) * inv + b1;
    ushort2 hh, ll;
    hh.x = f2bf(o0); ll.x = f2bf(o0 - bf2f(hh.x));
    hh.y = f2bf(o1); ll.y = f2bf(o1 - bf2f(hh.y));
    *(ushort2*)(oh + (size_t)row * DM + tid * 2) = hh;
    *(ushort2*)(ol + (size_t)row * DM + tid * 2) = ll;
}

// ---------------- hi/lo split (full) ----------------
__global__ __launch_bounds__(256)
void split2_kernel(const float* __restrict__ x, unsigned short* __restrict__ hi,
                   unsigned short* __restrict__ lo) {
    int i = blockIdx.x * 256 + threadIdx.x;   // one float4 each
    float4 v = *(const float4*)(x + (size_t)i * 4);
    ushort4 h, l;
    h.x = f2bf(v.x); l.x = f2bf(v.x - bf2f(h.x));
    h.y = f2bf(v.y); l.y = f2bf(v.y - bf2f(h.y));
    h.z = f2bf(v.z); l.z = f2bf(v.z - bf2f(h.z));
    h.w = f2bf(v.w); l.w = f2bf(v.w - bf2f(h.w));
    *(ushort4*)(hi + (size_t)i * 4) = h;
    *(ushort4*)(lo + (size_t)i * 4) = l;
}

// ---------------- hi-only split ----------------
__global__ __launch_bounds__(256)
void split1_kernel(const float* __restrict__ x, unsigned short* __restrict__ hi) {
    int i = blockIdx.x * 256 + threadIdx.x;
    float4 v = *(const float4*)(x + (size_t)i * 4);
    ushort4 h;
    h.x = f2bf(v.x); h.y = f2bf(v.y); h.z = f2bf(v.z); h.w = f2bf(v.w);
    *(ushort4*)(hi + (size_t)i * 4) = h;
}

// ---------------- W transpose + hi/lo split: Wt[n][k] = W[k][n] ----------------
__global__ __launch_bounds__(256)
void wsplit_kernel(const float* __restrict__ W, unsigned short* __restrict__ th,
                   unsigned short* __restrict__ tl) {
    __shared__ float ts[32][33];
    int k0 = blockIdx.y * 32, n0 = blockIdx.x * 32;
    int t = threadIdx.x;
    int r = t >> 3, c = (t & 7) * 4;
    float4 v = *(const float4*)(W + (size_t)(k0 + r) * 512 + n0 + c);
    ts[r][c] = v.x; ts[r][c + 1] = v.y; ts[r][c + 2] = v.z; ts[r][c + 3] = v.w;
    __syncthreads();
    float a0 = ts[c + 0][r], a1 = ts[c + 1][r], a2 = ts[c + 2][r], a3 = ts[c + 3][r];
    ushort4 h, l;
    h.x = f2bf(a0); l.x = f2bf(a0 - bf2f(h.x));
    h.y = f2bf(a1); l.y = f2bf(a1 - bf2f(h.y));
    h.z = f2bf(a2); l.z = f2bf(a2 - bf2f(h.z));
    h.w = f2bf(a3); l.w = f2bf(a3 - bf2f(h.w));
    *(ushort4*)(th + (size_t)(n0 + r) * 512 + k0 + c) = h;
    *(ushort4*)(tl + (size_t)(n0 + r) * 512 + k0 + c) = l;
}

// ---------------- MFMA split GEMM: C[16384 x 512] = A @ W + bias ----------------
template<int TERMS>
__global__ __launch_bounds__(256, 2)
void gemm_mfma(const unsigned short* __restrict__ Ah, const unsigned short* __restrict__ Al,
               const unsigned short* __restrict__ Bh, const unsigned short* __restrict__ Bl,
               const float* __restrict__ bias, float* __restrict__ C) {
    __shared__ __align__(16) unsigned short smem[20480];  // 40KB
    unsigned short* sAh = smem;              // [128][40]
    unsigned short* sAl = smem + 5120;
    unsigned short* sBh = smem + 10240;
    unsigned short* sBl = smem + 15360;

    int orig = blockIdx.x + 4 * blockIdx.y;          // 512 blocks
    int j = (orig & 7) * 64 + (orig >> 3);
    int n0 = (j & 3) * 128, m0 = (j >> 2) * 128;

    int tid = threadIdx.x;
    int lane = tid & 63, wv = tid >> 6;
    int wr = wv >> 1, wc = wv & 1;
    int lrow = lane & 15;
    int kofs = (lane >> 4) * 8;

    int f0 = tid, f1 = tid + 256;
    int row0 = f0 >> 2, c0 = (f0 & 3) * 8;
    int row1 = f1 >> 2, c1 = (f1 & 3) * 8;

    f32x4 acc[4][4];
#pragma unroll
    for (int mf = 0; mf < 4; mf++)
#pragma unroll
        for (int nf = 0; nf < 4; nf++) acc[mf][nf] = (f32x4){0.f, 0.f, 0.f, 0.f};

    short8 rAh0, rAh1, rAl0, rAl1, rBh0, rBh1, rBl0, rBl1;

    auto LOAD = [&](int kt) {
        int k0 = kt * 32;
        rAh0 = *(const short8*)(Ah + (size_t)(m0 + row0) * 512 + k0 + c0);
        rAh1 = *(const short8*)(Ah + (size_t)(m0 + row1) * 512 + k0 + c1);
        if (TERMS == 3) {
            rAl0 = *(const short8*)(Al + (size_t)(m0 + row0) * 512 + k0 + c0);
            rAl1 = *(const short8*)(Al + (size_t)(m0 + row1) * 512 + k0 + c1);
        }
        rBh0 = *(const short8*)(Bh + (size_t)(n0 + row0) * 512 + k0 + c0);
        rBh1 = *(const short8*)(Bh + (size_t)(n0 + row1) * 512 + k0 + c1);
        rBl0 = *(const short8*)(Bl + (size_t)(n0 + row0) * 512 + k0 + c0);
        rBl1 = *(const short8*)(Bl + (size_t)(n0 + row1) * 512 + k0 + c1);
    };
    auto STORE = [&]() {
        *(short8*)&sAh[row0 * 40 + c0] = rAh0;
        *(short8*)&sAh[row1 * 40 + c1] = rAh1;
        if (TERMS == 3) {
            *(short8*)&sAl[row0 * 40 + c0] = rAl0;
            *(short8*)&sAl[row1 * 40 + c1] = rAl1;
        }
        *(short8*)&sBh[row0 * 40 + c0] = rBh0;
        *(short8*)&sBh[row1 * 40 + c1] = rBh1;
        *(short8*)&sBl[row0 * 40 + c0] = rBl0;
        *(short8*)&sBl[row1 * 40 + c1] = rBl1;
    };

    int abase = (wr * 64 + lrow) * 40 + kofs;
    int bbase = (wc * 64 + lrow) * 40 + kofs;

    LOAD(0);
    for (int kt = 0; kt < 16; kt++) {
        STORE();
        __syncthreads();
        if (kt < 15) LOAD(kt + 1);
        short8 ah[4], al[4], bh[4], bl[4];
#pragma unroll
        for (int mf = 0; mf < 4; mf++) {
            ah[mf] = *(const short8*)&sAh[abase + mf * 640];
            if (TERMS == 3) al[mf] = *(const short8*)&sAl[abase + mf * 640];
        }
#pragma unroll
        for (int nf = 0; nf < 4; nf++) {
            bh[nf] = *(const short8*)&sBh[bbase + nf * 640];
            bl[nf] = *(const short8*)&sBl[bbase + nf * 640];
        }
#pragma unroll
        for (int mf = 0; mf < 4; mf++)
#pragma unroll
            for (int nf = 0; nf < 4; nf++) {
                acc[mf][nf] = MFMA_BF16(ah[mf], bh[nf], acc[mf][nf]);
                acc[mf][nf] = MFMA_BF16(ah[mf], bl[nf], acc[mf][nf]);
                if (TERMS == 3) acc[mf][nf] = MFMA_BF16(al[mf], bh[nf], acc[mf][nf]);
            }
        __syncthreads();
    }

    int crow0 = m0 + wr * 64 + (lane >> 4) * 4;
    int ccol0 = n0 + wc * 64 + lrow;
    float bb[4];
#pragma unroll
    for (int nf = 0; nf < 4; nf++) bb[nf] = bias[ccol0 + nf * 16];
#pragma unroll
    for (int mf = 0; mf < 4; mf++)
#pragma unroll
        for (int nf = 0; nf < 4; nf++)
#pragma unroll
            for (int r = 0; r < 4; r++)
                C[(size_t)(crow0 + mf * 16 + r) * 512 + ccol0 + nf * 16] =
                    acc[mf][nf][r] + bb[nf];
}

// ---------------- sampled QK^T -> M (direct-gather, XCD-pinned) ----------------
// Block = one (b,i); b = blockIdx.x & 7 pins each batch's K panel to one XCD L2.
// Wave w owns heads 2w,2w+1; 16-lane groups gather K float4 segs and shfl-reduce.
__global__ __launch_bounds__(256)
void sample_m_kernel(const float* __restrict__ q, const float* __restrict__ k,
                     const int* __restrict__ idx, float* __restrict__ M) {
    int id = blockIdx.x;
    int b = id & 7;
    int i = id >> 3;
    int tid = threadIdx.x;
    int wv = tid >> 6, lane = tid & 63;
    int jg4 = lane >> 4;      // which j within group of 4
    int dl = lane & 15;       // d-chunk lane (16 x float4 = 64 floats)
    __shared__ float dots[H_][SK];
    __shared__ int idxs[SK];
    if (tid < SK) idxs[tid] = idx[i * SK + tid];
    __syncthreads();
    const float* qrow = q + ((size_t)b * L + i) * DM;
#pragma unroll
    for (int hh = 0; hh < 2; hh++) {
        int h = wv * 2 + hh;
        float4 qv = *(const float4*)(qrow + h * DH + dl * 4);
#pragma unroll
        for (int jg = 0; jg < 6; jg++) {
            int j = jg * 4 + jg4;
            int row = idxs[j];
            float4 kv = *(const float4*)(k + ((size_t)b * L + row) * DM + h * DH + dl * 4);
            float s = qv.x * kv.x + qv.y * kv.y + qv.z * kv.z + qv.w * kv.w;
            s += __shfl_xor(s, 1, 64);
            s += __shfl_xor(s, 2, 64);
            s += __shfl_xor(s, 4, 64);
            s += __shfl_xor(s, 8, 64);
            if (dl == 0) dots[h][j] = s;
        }
    }
    __syncthreads();
    if (tid < H_) {
        float mx = -1e30f, sm = 0.f;
#pragma unroll
        for (int jj = 0; jj < SK; jj++) { float v = dots[tid][jj]; mx = fmaxf(mx, v); sm += v; }
        M[((size_t)b * H_ + tid) * L + i] = mx - sm * (1.0f / L);
    }
}

// ---------------- top-24 per (b,h), low-index tie-break ----------------
__global__ __launch_bounds__(256)
void topk_kernel(const float* __restrict__ M, int* __restrict__ mtop) {
    int bh = blockIdx.x;
    __shared__ float vals[L];
    __shared__ float rv[4];
    __shared__ int ri[4];
    int tid = threadIdx.x;
    const float* Mr = M + (size_t)bh * L;
    for (int t = tid; t < L; t += 256) vals[t] = Mr[t];
    __syncthreads();
    for (int it = 0; it < NTOP; it++) {
        float bv = -1e30f; int bi = 0x7fffffff;
        for (int t = tid; t < L; t += 256) {
            float v = vals[t];
            if (v > bv || (v == bv && t < bi)) { bv = v; bi = t; }
        }
        for (int o = 32; o > 0; o >>= 1) {
            float ov = __shfl_down(bv, o, 64);
            int oi = __shfl_down(bi, o, 64);
            if (ov > bv || (ov == bv && oi < bi)) { bv = ov; bi = oi; }
        }
        int wid = tid >> 6, lane = tid & 63;
        if (lane == 0) { rv[wid] = bv; ri[wid] = bi; }
        __syncthreads();
        if (tid == 0) {
            float fbv = rv[0]; int fbi = ri[0];
            for (int wv = 1; wv < 4; wv++)
                if (rv[wv] > fbv || (rv[wv] == fbv && ri[wv] < fbi)) { fbv = rv[wv]; fbi = ri[wv]; }
            mtop[bh * NTOP + it] = fbi;
            vals[fbi] = -1e30f;
        }
        __syncthreads();
    }
}

// ---------------- padding cumsum ----------------
__global__ __launch_bounds__(256)
void padscan_kernel(const float* __restrict__ pad, float* __restrict__ denom) {
    int b = blockIdx.x;
    __shared__ float tot[256];
    int tid = threadIdx.x;
    const float* p = pad + (size_t)b * L;
    float loc[8];
    float s = 0.f;
#pragma unroll
    for (int u = 0; u < 8; u++) { s += p[tid * 8 + u]; loc[u] = s; }
    tot[tid] = s;
    __syncthreads();
    for (int off = 1; off < 256; off <<= 1) {
        float add = (tid >= off) ? tot[tid - off] : 0.f;
        __syncthreads();
        tot[tid] += add;
        __syncthreads();
    }
    float excl = tot[tid] - s;
#pragma unroll
    for (int u = 0; u < 8; u++) denom[(size_t)b * L + tid * 8 + u] = excl + loc[u];
}

// ---------------- cumulative average of V (3 passes) ----------------
__global__ __launch_bounds__(512)
void vavg1_kernel(const float* __restrict__ v, float* __restrict__ pre, float* __restrict__ csum) {
    int c = blockIdx.x, b = blockIdx.y, d = threadIdx.x;
    size_t base = ((size_t)b * L + c * 128) * DM + d;
    float acc = 0.f;
    for (int t = 0; t < 128; t++) {
        acc += v[base + (size_t)t * DM];
        pre[base + (size_t)t * DM] = acc;
    }
    csum[((size_t)b * 16 + c) * DM + d] = acc;
}

__global__ __launch_bounds__(512)
void vavg2_kernel(float* __restrict__ csum) {
    int b = blockIdx.x, d = threadIdx.x;
    float run = 0.f;
    for (int c = 0; c < 16; c++) {
        size_t o = ((size_t)b * 16 + c) * DM + d;
        float t = csum[o];
        csum[o] = run;
        run += t;
    }
}

// vavg3 now emits bf16-hi directly (feeds only the final 2-term GEMM)
__global__ __launch_bounds__(512)
void vavg3_kernel(const float* __restrict__ pre, const float* __restrict__ csum,
                  const float* __restrict__ denom, unsigned short* __restrict__ out_h) {
    int c = blockIdx.x, b = blockIdx.y, d = threadIdx.x;
    float off = csum[((size_t)b * 16 + c) * DM + d];
    size_t base = ((size_t)b * L + c * 128) * DM + d;
    for (int t = 0; t < 128; t++) {
        float dn = denom[(size_t)b * L + c * 128 + t] + 1e-12f;
        out_h[base + (size_t)t * DM] = f2bf((pre[base + (size_t)t * DM] + off) / dn);
    }
}

// ---------------- split-chunk sparse attention ----------------
__global__ __launch_bounds__(256)
void attn_chunk_kernel(const float* __restrict__ q, const float* __restrict__ k,
                       const float* __restrict__ v, const int* __restrict__ mtop,
                       const float* __restrict__ pad,
                       float* __restrict__ part_m, float* __restrict__ part_s,
                       float* __restrict__ part_acc) {
    int c = blockIdx.x, bh = blockIdx.y;
    int b = bh >> 3, h = bh & 7;
    int j0 = c * CHUNK;
    __shared__ float Ks[CHUNK][68];
    __shared__ float Pst[CHUNK][28];
    __shared__ int   iq_s[24];
    __shared__ int   lim_s[24];
    __shared__ float scl_s[24];
    int tid = threadIdx.x;
    if (tid < 24) {
        int iq = mtop[bh * NTOP + tid];
        iq_s[tid] = iq;
        bool ok = pad[(size_t)b * L + iq] != 0.f;
        lim_s[tid] = ok ? iq : (L - 1);
        scl_s[tid] = ok ? 0.044194173824159216f : 0.f;
    }
#pragma unroll
    for (int l = 0; l < 8; l++) {
        int f = tid + l * 256;
        int row = f >> 4, seg = (f & 15) * 4;
        *(float4*)&Ks[row][seg] =
            *(const float4*)(k + ((size_t)b * L + j0 + row) * DM + h * DH + seg);
    }
    __syncthreads();

    int uslot = tid >> 3, jslot = tid & 7;
    if (uslot < 24) {
        float4 qv[16];
        const float* qp = q + ((size_t)b * L + iq_s[uslot]) * DM + h * DH;
#pragma unroll
        for (int dd = 0; dd < 16; dd++) qv[dd] = ((const float4*)qp)[dd];
        int lim = lim_s[uslot];
        float sc = scl_s[uslot];
        float vals[16];
        float lmax = -1e30f;
#pragma unroll
        for (int i = 0; i < 16; i++) {
            int j = jslot + 8 * i;
            float s = 0.f;
#pragma unroll
            for (int dd = 0; dd < 16; dd++) {
                float4 kv = *(const float4*)&Ks[j][dd * 4];
                s = fmaf(qv[dd].x, kv.x, s);
                s = fmaf(qv[dd].y, kv.y, s);
                s = fmaf(qv[dd].z, kv.z, s);
                s = fmaf(qv[dd].w, kv.w, s);
            }
            float sv = (j0 + j <= lim) ? s * sc : -1e30f;
            vals[i] = sv;
            lmax = fmaxf(lmax, sv);
        }
        lmax = fmaxf(lmax, __shfl_xor(lmax, 1, 64));
        lmax = fmaxf(lmax, __shfl_xor(lmax, 2, 64));
        lmax = fmaxf(lmax, __shfl_xor(lmax, 4, 64));
        bool any = lmax > -1e29f;
        float lsum = 0.f;
#pragma unroll
        for (int i = 0; i < 16; i++) {
            float e = any ? __expf(vals[i] - lmax) : 0.f;
            Pst[jslot + 8 * i][uslot] = e;
            lsum += e;
        }
        lsum += __shfl_xor(lsum, 1, 64);
        lsum += __shfl_xor(lsum, 2, 64);
        lsum += __shfl_xor(lsum, 4, 64);
        if (jslot == 0) {
            part_m[(bh * NTOP + uslot) * NCH + c] = lmax;
            part_s[(bh * NTOP + uslot) * NCH + c] = lsum;
        }
    }
    __syncthreads();
#pragma unroll
    for (int l = 0; l < 8; l++) {
        int f = tid + l * 256;
        int row = f >> 4, seg = (f & 15) * 4;
        *(float4*)&Ks[row][seg] =
            *(const float4*)(v + ((size_t)b * L + j0 + row) * DM + h * DH + seg);
    }
    __syncthreads();
    int d = tid & 63, g = tid >> 6;
    float acc[6] = {0.f, 0.f, 0.f, 0.f, 0.f, 0.f};
    for (int j = 0; j < CHUNK; j++) {
        float vv = Ks[j][d];
        float2 p01 = *(float2*)&Pst[j][6 * g];
        float2 p23 = *(float2*)&Pst[j][6 * g + 2];
        float2 p45 = *(float2*)&Pst[j][6 * g + 4];
        acc[0] = fmaf(p01.x, vv, acc[0]);
        acc[1] = fmaf(p01.y, vv, acc[1]);
        acc[2] = fmaf(p23.x, vv, acc[2]);
        acc[3] = fmaf(p23.y, vv, acc[3]);
        acc[4] = fmaf(p45.x, vv, acc[4]);
        acc[5] = fmaf(p45.y, vv, acc[5]);
    }
#pragma unroll
    for (int up = 0; up < 6; up++) {
        int u = g * 6 + up;
        part_acc[((size_t)(bh * NTOP + u) * NCH + c) * 64 + d] = acc[up];
    }
}

// merge 16 chunk partials per (bh,u); scatter bf16 into pre_h
__global__ __launch_bounds__(256)
void attn_merge_kernel(const float* __restrict__ part_m, const float* __restrict__ part_s,
                       const float* __restrict__ part_acc, const int* __restrict__ mtop,
                       unsigned short* __restrict__ pre_h) {
    int ug = blockIdx.x;
    int bh = blockIdx.y;
    int b = bh >> 3, h = bh & 7;
    int tid = threadIdx.x;
    int u = ug * 4 + (tid >> 6);
    int d = tid & 63;
    int base = (bh * NTOP + u) * NCH;
    float m = -1e30f;
#pragma unroll
    for (int c = 0; c < NCH; c++) m = fmaxf(m, part_m[base + c]);
    float s = 0.f, o = 0.f;
#pragma unroll
    for (int c = 0; c < NCH; c++) {
        float w = __expf(part_m[base + c] - m);
        s += part_s[base + c] * w;
        o = fmaf(part_acc[(size_t)(base + c) * 64 + d], w, o);
    }
    o /= s;
    int iq = mtop[bh * NTOP + u];
    pre_h[((size_t)b * L + iq) * DM + h * DH + d] = f2bf(o);
}

extern "C" void kernel_launch(void* const* d_in, const int* in_sizes, int n_in,
                              void* d_out, int out_size, void* d_ws, size_t ws_size,
                              hipStream_t stream) {
    const float* queries = (const float*)d_in[0];
    const float* keys    = (const float*)d_in[1];
    const float* values  = (const float*)d_in[2];
    const float* pad     = (const float*)d_in[3];
    const float* Wq = (const float*)d_in[4];  const float* bq = (const float*)d_in[5];
    const float* Wk = (const float*)d_in[6];  const float* bk = (const float*)d_in[7];
    const float* Wv = (const float*)d_in[8];  const float* bv = (const float*)d_in[9];
    const float* Wf = (const float*)d_in[10]; const float* bfv = (const float*)d_in[11];
    const float* qlnw = (const float*)d_in[12]; const float* qlnb = (const float*)d_in[13];
    const float* flnw = (const float*)d_in[14]; const float* flnb = (const float*)d_in[15];
    const int* idx = (const int*)d_in[16];

    float* ws = (float*)d_ws;
    const size_t NE = (size_t)B_ * L * DM;   // 8388608
    float* qb    = ws;
    float* kb    = ws + NE;
    float* vb    = ws + 2 * NE;
    float* pre   = ws + 3 * NE;
    float* Mbuf  = ws + 4 * NE;                      // 64*2048
    float* denom = Mbuf + (size_t)B_ * H_ * L;       // 8*2048
    float* csum  = denom + (size_t)B_ * L;           // 8*16*512
    int*   mtop  = (int*)(csum + (size_t)B_ * 16 * DM);
    unsigned short* bfr = (unsigned short*)(mtop + 2048);
    unsigned short* keys_h = bfr;
    unsigned short* keys_l = bfr + NE;
    unsigned short* vals_h = bfr + 2 * NE;
    unsigned short* wts    = bfr + 3 * NE;
    unsigned short* wq_h = wts;              unsigned short* wq_l = wts + 262144;
    unsigned short* wk_h = wts + 2 * 262144; unsigned short* wk_l = wts + 3 * 262144;
    unsigned short* wv_h = wts + 4 * 262144; unsigned short* wv_l = wts + 5 * 262144;
    unsigned short* wf_h = wts + 6 * 262144; unsigned short* wf_l = wts + 7 * 262144;
    unsigned short* pre_h = keys_h;          // alias: keys dead after k-GEMM

    float* tmp = (float*)d_out;
    unsigned short* lnq_h = (unsigned short*)d_out;   // d_out as bf16 scratch
    unsigned short* lnq_l = lnq_h + NE;
    float* part_m   = tmp;                            // later: attn partials
    float* part_s   = part_m + 64 * NTOP * NCH;
    float* part_acc = part_s + 64 * NTOP * NCH;

    padscan_kernel<<<B_, 256, 0, stream>>>(pad, denom);
    ln_split_kernel<<<B_ * L, 256, 0, stream>>>(queries, qlnw, qlnb, lnq_h, lnq_l);
    split2_kernel<<<NE / 1024, 256, 0, stream>>>(keys, keys_h, keys_l);
    split1_kernel<<<NE / 1024, 256, 0, stream>>>(values, vals_h);
    dim3 gw(16, 16);
    wsplit_kernel<<<gw, 256, 0, stream>>>(Wq, wq_h, wq_l);
    wsplit_kernel<<<gw, 256, 0, stream>>>(Wk, wk_h, wk_l);
    wsplit_kernel<<<gw, 256, 0, stream>>>(Wv, wv_h, wv_l);
    wsplit_kernel<<<gw, 256, 0, stream>>>(Wf, wf_h, wf_l);

    dim3 gg(4, 128);
    gemm_mfma<3><<<gg, 256, 0, stream>>>(lnq_h, lnq_l, wq_h, wq_l, bq, qb);
    gemm_mfma<3><<<gg, 256, 0, stream>>>(keys_h, keys_l, wk_h, wk_l, bk, kb);
    gemm_mfma<2><<<gg, 256, 0, stream>>>(vals_h, nullptr, wv_h, wv_l, bv, vb);

    sample_m_kernel<<<B_ * L, 256, 0, stream>>>(qb, kb, idx, Mbuf);
    topk_kernel<<<B_ * H_, 256, 0, stream>>>(Mbuf, mtop);
    dim3 gv(16, B_);
    vavg1_kernel<<<gv, 512, 0, stream>>>(vb, pre, csum);
    vavg2_kernel<<<B_, 512, 0, stream>>>(csum);
    vavg3_kernel<<<gv, 512, 0, stream>>>(pre, csum, denom, pre_h);
    dim3 gc(NCH, 64);
    attn_chunk_kernel<<<gc, 256, 0, stream>>>(qb, kb, vb, mtop, pad,
                                              part_m, part_s, part_acc);
    dim3 gmg(6, 64);
    attn_merge_kernel<<<gmg, 256, 0, stream>>>(part_m, part_s, part_acc, mtop, pre_h);
    gemm_mfma<2><<<gg, 256, 0, stream>>>(pre_h, nullptr, wf_h, wf_l, bfv, (float*)d_out);
    ln_kernel<<<B_ * L, 256, 0, stream>>>((float*)d_out, flnw, flnb, (float*)d_out);
}

// Round 5
// 323.304 us; speedup vs baseline: 2.5708x; 1.1072x over previous
//
#include <hip/hip_runtime.h>
#include <math.h>

#define L 2048
#define DM 512
#define B_ 8
#define H_ 8
#define DH 64
#define SK 24
#define NTOP 24
#define CHUNK 128
#define NCH (L / CHUNK)   // 16
#define VC 32             // vavg chunks
#define VR 64             // rows per vavg chunk

typedef __attribute__((ext_vector_type(8))) short short8;
typedef __attribute__((ext_vector_type(8))) __bf16 bf16x8;
typedef __attribute__((ext_vector_type(4))) float f32x4;

__device__ inline unsigned short f2bf(float x) {
    unsigned u = __float_as_uint(x);
    unsigned r = (u + 0x7FFFu + ((u >> 16) & 1u)) >> 16;
    return (unsigned short)r;
}
__device__ inline float bf2f(unsigned short h) {
    return __uint_as_float(((unsigned)h) << 16);
}

__device__ inline f32x4 MFMA_BF16(short8 a, short8 b, f32x4 c) {
    return __builtin_amdgcn_mfma_f32_16x16x32_bf16(
        __builtin_bit_cast(bf16x8, a), __builtin_bit_cast(bf16x8, b), c, 0, 0, 0);
}

// ---------------- reduce helpers ----------------
__device__ inline float waveReduceSum(float v) {
    for (int o = 32; o > 0; o >>= 1) v += __shfl_down(v, o, 64);
    return v;
}
__device__ inline float waveReduceMax(float v) {
    for (int o = 32; o > 0; o >>= 1) v = fmaxf(v, __shfl_down(v, o, 64));
    return v;
}

// ---------------- LayerNorm (row-wise, 512 cols) f32 out ----------------
__global__ __launch_bounds__(256)
void ln_kernel(const float* __restrict__ x, const float* __restrict__ w,
               const float* __restrict__ bvec, float* __restrict__ out) {
    int row = blockIdx.x;
    const float* xr = x + (size_t)row * DM;
    float* orow = out + (size_t)row * DM;
    int tid = threadIdx.x;
    float2 v = *(const float2*)(xr + tid * 2);
    float s = v.x + v.y;
    float sq = v.x * v.x + v.y * v.y;
    __shared__ float red[8];
    float ws = waveReduceSum(s);
    float wq = waveReduceSum(sq);
    int wid = tid >> 6, lane = tid & 63;
    if (lane == 0) { red[wid] = ws; red[4 + wid] = wq; }
    __syncthreads();
    float tot = red[0] + red[1] + red[2] + red[3];
    float totq = red[4] + red[5] + red[6] + red[7];
    float mean = tot * (1.0f / DM);
    float var = totq * (1.0f / DM) - mean * mean;
    float inv = rsqrtf(var + 1e-8f);
    float w0 = w[tid * 2], w1 = w[tid * 2 + 1];
    float b0 = bvec[tid * 2], b1 = bvec[tid * 2 + 1];
    float2 o;
    o.x = w0 * (v.x - mean) * inv + b0;
    o.y = w1 * (v.y - mean) * inv + b1;
    *(float2*)(orow + tid * 2) = o;
}

// ---------------- LayerNorm with bf16 hi/lo split output ----------------
__global__ __launch_bounds__(256)
void ln_split_kernel(const float* __restrict__ x, const float* __restrict__ w,
                     const float* __restrict__ bvec,
                     unsigned short* __restrict__ oh, unsigned short* __restrict__ ol) {
    int row = blockIdx.x;
    const float* xr = x + (size_t)row * DM;
    int tid = threadIdx.x;
    float2 v = *(const float2*)(xr + tid * 2);
    float s = v.x + v.y;
    float sq = v.x * v.x + v.y * v.y;
    __shared__ float red[8];
    float ws = waveReduceSum(s);
    float wq = waveReduceSum(sq);
    int wid = tid >> 6, lane = tid & 63;
    if (lane == 0) { red[wid] = ws; red[4 + wid] = wq; }
    __syncthreads();
    float tot = red[0] + red[1] + red[2] + red[3];
    float totq = red[4] + red[5] + red[6] + red[7];
    float mean = tot * (1.0f / DM);
    float var = totq * (1.0f / DM) - mean * mean;
    float inv = rsqrtf(var + 1e-8f);
    float w0 = w[tid * 2], w1 = w[tid * 2 + 1];
    float b0 = bvec[tid * 2], b1 = bvec[tid * 2 + 1];
    float o0 = w0 * (v.x - mean) * inv + b0;
    float o1 = w1 * (v.y - mean) * inv + b1;
    ushort2 hh, ll;
    hh.x = f2bf(o0); ll.x = f2bf(o0 - bf2f(hh.x));
    hh.y = f2bf(o1); ll.y = f2bf(o1 - bf2f(hh.y));
    *(ushort2*)(oh + (size_t)row * DM + tid * 2) = hh;
    *(ushort2*)(ol + (size_t)row * DM + tid * 2) = ll;
}

// ---------------- hi/lo split (full) ----------------
__global__ __launch_bounds__(256)
void split2_kernel(const float* __restrict__ x, unsigned short* __restrict__ hi,
                   unsigned short* __restrict__ lo) {
    int i = blockIdx.x * 256 + threadIdx.x;   // one float4 each
    float4 v = *(const float4*)(x + (size_t)i * 4);
    ushort4 h, l;
    h.x = f2bf(v.x); l.x = f2bf(v.x - bf2f(h.x));
    h.y = f2bf(v.y); l.y = f2bf(v.y - bf2f(h.y));
    h.z = f2bf(v.z); l.z = f2bf(v.z - bf2f(h.z));
    h.w = f2bf(v.w); l.w = f2bf(v.w - bf2f(h.w));
    *(ushort4*)(hi + (size_t)i * 4) = h;
    *(ushort4*)(lo + (size_t)i * 4) = l;
}

// ---------------- hi-only split ----------------
__global__ __launch_bounds__(256)
void split1_kernel(const float* __restrict__ x, unsigned short* __restrict__ hi) {
    int i = blockIdx.x * 256 + threadIdx.x;
    float4 v = *(const float4*)(x + (size_t)i * 4);
    ushort4 h;
    h.x = f2bf(v.x); h.y = f2bf(v.y); h.z = f2bf(v.z); h.w = f2bf(v.w);
    *(ushort4*)(hi + (size_t)i * 4) = h;
}

// ---------------- W transpose + hi/lo split: Wt[n][k] = W[k][n] ----------------
__global__ __launch_bounds__(256)
void wsplit_kernel(const float* __restrict__ W, unsigned short* __restrict__ th,
                   unsigned short* __restrict__ tl) {
    __shared__ float ts[32][33];
    int k0 = blockIdx.y * 32, n0 = blockIdx.x * 32;
    int t = threadIdx.x;
    int r = t >> 3, c = (t & 7) * 4;
    float4 v = *(const float4*)(W + (size_t)(k0 + r) * 512 + n0 + c);
    ts[r][c] = v.x; ts[r][c + 1] = v.y; ts[r][c + 2] = v.z; ts[r][c + 3] = v.w;
    __syncthreads();
    float a0 = ts[c + 0][r], a1 = ts[c + 1][r], a2 = ts[c + 2][r], a3 = ts[c + 3][r];
    ushort4 h, l;
    h.x = f2bf(a0); l.x = f2bf(a0 - bf2f(h.x));
    h.y = f2bf(a1); l.y = f2bf(a1 - bf2f(h.y));
    h.z = f2bf(a2); l.z = f2bf(a2 - bf2f(h.z));
    h.w = f2bf(a3); l.w = f2bf(a3 - bf2f(h.w));
    *(ushort4*)(th + (size_t)(n0 + r) * 512 + k0 + c) = h;
    *(ushort4*)(tl + (size_t)(n0 + r) * 512 + k0 + c) = l;
}

// ---------------- MFMA split GEMM: C[16384 x 512] = A @ W + bias ----------------
template<int TERMS>
__global__ __launch_bounds__(256, 2)
void gemm_mfma(const unsigned short* __restrict__ Ah, const unsigned short* __restrict__ Al,
               const unsigned short* __restrict__ Bh, const unsigned short* __restrict__ Bl,
               const float* __restrict__ bias, float* __restrict__ C) {
    __shared__ __align__(16) unsigned short smem[20480];  // 40KB
    unsigned short* sAh = smem;              // [128][40]
    unsigned short* sAl = smem + 5120;
    unsigned short* sBh = smem + 10240;
    unsigned short* sBl = smem + 15360;

    int orig = blockIdx.x + 4 * blockIdx.y;          // 512 blocks
    int j = (orig & 7) * 64 + (orig >> 3);
    int n0 = (j & 3) * 128, m0 = (j >> 2) * 128;

    int tid = threadIdx.x;
    int lane = tid & 63, wv = tid >> 6;
    int wr = wv >> 1, wc = wv & 1;
    int lrow = lane & 15;
    int kofs = (lane >> 4) * 8;

    int f0 = tid, f1 = tid + 256;
    int row0 = f0 >> 2, c0 = (f0 & 3) * 8;
    int row1 = f1 >> 2, c1 = (f1 & 3) * 8;

    f32x4 acc[4][4];
#pragma unroll
    for (int mf = 0; mf < 4; mf++)
#pragma unroll
        for (int nf = 0; nf < 4; nf++) acc[mf][nf] = (f32x4){0.f, 0.f, 0.f, 0.f};

    short8 rAh0, rAh1, rAl0, rAl1, rBh0, rBh1, rBl0, rBl1;

    auto LOAD = [&](int kt) {
        int k0 = kt * 32;
        rAh0 = *(const short8*)(Ah + (size_t)(m0 + row0) * 512 + k0 + c0);
        rAh1 = *(const short8*)(Ah + (size_t)(m0 + row1) * 512 + k0 + c1);
        if (TERMS == 3) {
            rAl0 = *(const short8*)(Al + (size_t)(m0 + row0) * 512 + k0 + c0);
            rAl1 = *(const short8*)(Al + (size_t)(m0 + row1) * 512 + k0 + c1);
        }
        rBh0 = *(const short8*)(Bh + (size_t)(n0 + row0) * 512 + k0 + c0);
        rBh1 = *(const short8*)(Bh + (size_t)(n0 + row1) * 512 + k0 + c1);
        rBl0 = *(const short8*)(Bl + (size_t)(n0 + row0) * 512 + k0 + c0);
        rBl1 = *(const short8*)(Bl + (size_t)(n0 + row1) * 512 + k0 + c1);
    };
    auto STORE = [&]() {
        *(short8*)&sAh[row0 * 40 + c0] = rAh0;
        *(short8*)&sAh[row1 * 40 + c1] = rAh1;
        if (TERMS == 3) {
            *(short8*)&sAl[row0 * 40 + c0] = rAl0;
            *(short8*)&sAl[row1 * 40 + c1] = rAl1;
        }
        *(short8*)&sBh[row0 * 40 + c0] = rBh0;
        *(short8*)&sBh[row1 * 40 + c1] = rBh1;
        *(short8*)&sBl[row0 * 40 + c0] = rBl0;
        *(short8*)&sBl[row1 * 40 + c1] = rBl1;
    };

    int abase = (wr * 64 + lrow) * 40 + kofs;
    int bbase = (wc * 64 + lrow) * 40 + kofs;

    LOAD(0);
    for (int kt = 0; kt < 16; kt++) {
        STORE();
        __syncthreads();
        if (kt < 15) LOAD(kt + 1);
        short8 ah[4], al[4], bh[4], bl[4];
#pragma unroll
        for (int mf = 0; mf < 4; mf++) {
            ah[mf] = *(const short8*)&sAh[abase + mf * 640];
            if (TERMS == 3) al[mf] = *(const short8*)&sAl[abase + mf * 640];
        }
#pragma unroll
        for (int nf = 0; nf < 4; nf++) {
            bh[nf] = *(const short8*)&sBh[bbase + nf * 640];
            bl[nf] = *(const short8*)&sBl[bbase + nf * 640];
        }
#pragma unroll
        for (int mf = 0; mf < 4; mf++)
#pragma unroll
            for (int nf = 0; nf < 4; nf++) {
                acc[mf][nf] = MFMA_BF16(ah[mf], bh[nf], acc[mf][nf]);
                acc[mf][nf] = MFMA_BF16(ah[mf], bl[nf], acc[mf][nf]);
                if (TERMS == 3) acc[mf][nf] = MFMA_BF16(al[mf], bh[nf], acc[mf][nf]);
            }
        __syncthreads();
    }

    int crow0 = m0 + wr * 64 + (lane >> 4) * 4;
    int ccol0 = n0 + wc * 64 + lrow;
    float bb[4];
#pragma unroll
    for (int nf = 0; nf < 4; nf++) bb[nf] = bias[ccol0 + nf * 16];
#pragma unroll
    for (int mf = 0; mf < 4; mf++)
#pragma unroll
        for (int nf = 0; nf < 4; nf++)
#pragma unroll
            for (int r = 0; r < 4; r++)
                C[(size_t)(crow0 + mf * 16 + r) * 512 + ccol0 + nf * 16] =
                    acc[mf][nf][r] + bb[nf];
}

// ---------------- sampled QK^T -> M (one wave per (b,i), full-row gathers) ----------------
// b = blockIdx & 7 pins each batch's K panel to one XCD's L2. Each lane holds 8
// floats of the Q row; per j the whole wave reads the full K row coalesced.
__global__ __launch_bounds__(256)
void sample_m_kernel(const float* __restrict__ q, const float* __restrict__ k,
                     const int* __restrict__ idx, float* __restrict__ M) {
    int bid = blockIdx.x;          // 4096
    int b = bid & 7;
    int ig = bid >> 3;             // 0..511
    int wv = threadIdx.x >> 6, lane = threadIdx.x & 63;
    int i = ig * 4 + wv;
    const float* qrow = q + ((size_t)b * L + i) * DM + lane * 8;
    float4 q0 = *(const float4*)qrow;
    float4 q1 = *(const float4*)(qrow + 4);
    int myidx = 0;
    if (lane < SK) myidx = idx[i * SK + lane];
    float mx = -1e30f, sm = 0.f;
#pragma unroll
    for (int j = 0; j < SK; j++) {
        int row = __shfl(myidx, j, 64);
        const float* kp = k + ((size_t)b * L + row) * DM + lane * 8;
        float4 k0 = *(const float4*)kp;
        float4 k1 = *(const float4*)(kp + 4);
        float s = q0.x * k0.x + q0.y * k0.y + q0.z * k0.z + q0.w * k0.w
                + q1.x * k1.x + q1.y * k1.y + q1.z * k1.z + q1.w * k1.w;
        s += __shfl_xor(s, 1, 64);
        s += __shfl_xor(s, 2, 64);
        s += __shfl_xor(s, 4, 64);
        mx = fmaxf(mx, s);
        sm += s;
    }
    if ((lane & 7) == 0) {
        int h = lane >> 3;
        M[((size_t)b * H_ + h) * L + i] = mx - sm * (1.0f / L);
    }
}

// ---------------- top-24 per (b,h), low-index tie-break ----------------
__global__ __launch_bounds__(256)
void topk_kernel(const float* __restrict__ M, int* __restrict__ mtop) {
    int bh = blockIdx.x;
    __shared__ float vals[L];
    __shared__ float rv[4];
    __shared__ int ri[4];
    int tid = threadIdx.x;
    const float* Mr = M + (size_t)bh * L;
    for (int t = tid; t < L; t += 256) vals[t] = Mr[t];
    __syncthreads();
    for (int it = 0; it < NTOP; it++) {
        float bv = -1e30f; int bi = 0x7fffffff;
        for (int t = tid; t < L; t += 256) {
            float v = vals[t];
            if (v > bv || (v == bv && t < bi)) { bv = v; bi = t; }
        }
        for (int o = 32; o > 0; o >>= 1) {
            float ov = __shfl_down(bv, o, 64);
            int oi = __shfl_down(bi, o, 64);
            if (ov > bv || (ov == bv && oi < bi)) { bv = ov; bi = oi; }
        }
        int wid = tid >> 6, lane = tid & 63;
        if (lane == 0) { rv[wid] = bv; ri[wid] = bi; }
        __syncthreads();
        if (tid == 0) {
            float fbv = rv[0]; int fbi = ri[0];
            for (int wv = 1; wv < 4; wv++)
                if (rv[wv] > fbv || (rv[wv] == fbv && ri[wv] < fbi)) { fbv = rv[wv]; fbi = ri[wv]; }
            mtop[bh * NTOP + it] = fbi;
            vals[fbi] = -1e30f;
        }
        __syncthreads();
    }
}

// ---------------- padding cumsum ----------------
__global__ __launch_bounds__(256)
void padscan_kernel(const float* __restrict__ pad, float* __restrict__ denom) {
    int b = blockIdx.x;
    __shared__ float tot[256];
    int tid = threadIdx.x;
    const float* p = pad + (size_t)b * L;
    float loc[8];
    float s = 0.f;
#pragma unroll
    for (int u = 0; u < 8; u++) { s += p[tid * 8 + u]; loc[u] = s; }
    tot[tid] = s;
    __syncthreads();
    for (int off = 1; off < 256; off <<= 1) {
        float add = (tid >= off) ? tot[tid - off] : 0.f;
        __syncthreads();
        tot[tid] += add;
        __syncthreads();
    }
    float excl = tot[tid] - s;
#pragma unroll
    for (int u = 0; u < 8; u++) denom[(size_t)b * L + tid * 8 + u] = excl + loc[u];
}

// ---------------- cumulative average of V (2 passes) ----------------
__global__ __launch_bounds__(256)
void vsum_kernel(const float* __restrict__ v, float* __restrict__ csum) {
    int c = blockIdx.x, b = blockIdx.y;
    int d = blockIdx.z * 256 + threadIdx.x;
    size_t base = ((size_t)b * L + c * VR) * DM + d;
    float acc = 0.f;
    for (int t = 0; t < VR; t++) acc += v[base + (size_t)t * DM];
    csum[((size_t)b * VC + c) * DM + d] = acc;
}

__global__ __launch_bounds__(256)
void vavg_kernel(const float* __restrict__ v, const float* __restrict__ csum,
                 const float* __restrict__ denom, unsigned short* __restrict__ out_h) {
    int c = blockIdx.x, b = blockIdx.y;
    int d = blockIdx.z * 256 + threadIdx.x;
    float acc = 0.f;
    for (int cc = 0; cc < c; cc++) acc += csum[((size_t)b * VC + cc) * DM + d];
    size_t base = ((size_t)b * L + c * VR) * DM + d;
    for (int t = 0; t < VR; t++) {
        acc += v[base + (size_t)t * DM];
        float dn = denom[(size_t)b * L + c * VR + t] + 1e-12f;
        out_h[base + (size_t)t * DM] = f2bf(acc / dn);
    }
}

// ---------------- split-chunk sparse attention ----------------
__global__ __launch_bounds__(256)
void attn_chunk_kernel(const float* __restrict__ q, const float* __restrict__ k,
                       const float* __restrict__ v, const int* __restrict__ mtop,
                       const float* __restrict__ pad,
                       float* __restrict__ part_m, float* __restrict__ part_s,
                       float* __restrict__ part_acc) {
    int c = blockIdx.x, bh = blockIdx.y;
    int b = bh >> 3, h = bh & 7;
    int j0 = c * CHUNK;
    __shared__ float Ks[CHUNK][68];
    __shared__ float Pst[CHUNK][28];
    __shared__ int   iq_s[24];
    __shared__ int   lim_s[24];
    __shared__ float scl_s[24];
    int tid = threadIdx.x;
    if (tid < 24) {
        int iq = mtop[bh * NTOP + tid];
        iq_s[tid] = iq;
        bool ok = pad[(size_t)b * L + iq] != 0.f;
        lim_s[tid] = ok ? iq : (L - 1);
        scl_s[tid] = ok ? 0.044194173824159216f : 0.f;
    }
#pragma unroll
    for (int l = 0; l < 8; l++) {
        int f = tid + l * 256;
        int row = f >> 4, seg = (f & 15) * 4;
        *(float4*)&Ks[row][seg] =
            *(const float4*)(k + ((size_t)b * L + j0 + row) * DM + h * DH + seg);
    }
    __syncthreads();

    int uslot = tid >> 3, jslot = tid & 7;
    if (uslot < 24) {
        float4 qv[16];
        const float* qp = q + ((size_t)b * L + iq_s[uslot]) * DM + h * DH;
#pragma unroll
        for (int dd = 0; dd < 16; dd++) qv[dd] = ((const float4*)qp)[dd];
        int lim = lim_s[uslot];
        float sc = scl_s[uslot];
        float vals[16];
        float lmax = -1e30f;
#pragma unroll
        for (int i = 0; i < 16; i++) {
            int j = jslot + 8 * i;
            float s = 0.f;
#pragma unroll
            for (int dd = 0; dd < 16; dd++) {
                float4 kv = *(const float4*)&Ks[j][dd * 4];
                s = fmaf(qv[dd].x, kv.x, s);
                s = fmaf(qv[dd].y, kv.y, s);
                s = fmaf(qv[dd].z, kv.z, s);
                s = fmaf(qv[dd].w, kv.w, s);
            }
            float sv = (j0 + j <= lim) ? s * sc : -1e30f;
            vals[i] = sv;
            lmax = fmaxf(lmax, sv);
        }
        lmax = fmaxf(lmax, __shfl_xor(lmax, 1, 64));
        lmax = fmaxf(lmax, __shfl_xor(lmax, 2, 64));
        lmax = fmaxf(lmax, __shfl_xor(lmax, 4, 64));
        bool any = lmax > -1e29f;
        float lsum = 0.f;
#pragma unroll
        for (int i = 0; i < 16; i++) {
            float e = any ? __expf(vals[i] - lmax) : 0.f;
            Pst[jslot + 8 * i][uslot] = e;
            lsum += e;
        }
        lsum += __shfl_xor(lsum, 1, 64);
        lsum += __shfl_xor(lsum, 2, 64);
        lsum += __shfl_xor(lsum, 4, 64);
        if (jslot == 0) {
            part_m[(bh * NTOP + uslot) * NCH + c] = lmax;
            part_s[(bh * NTOP + uslot) * NCH + c] = lsum;
        }
    }
    __syncthreads();
#pragma unroll
    for (int l = 0; l < 8; l++) {
        int f = tid + l * 256;
        int row = f >> 4, seg = (f & 15) * 4;
        *(float4*)&Ks[row][seg] =
            *(const float4*)(v + ((size_t)b * L + j0 + row) * DM + h * DH + seg);
    }
    __syncthreads();
    int d = tid & 63, g = tid >> 6;
    float acc[6] = {0.f, 0.f, 0.f, 0.f, 0.f, 0.f};
    for (int j = 0; j < CHUNK; j++) {
        float vv = Ks[j][d];
        float2 p01 = *(float2*)&Pst[j][6 * g];
        float2 p23 = *(float2*)&Pst[j][6 * g + 2];
        float2 p45 = *(float2*)&Pst[j][6 * g + 4];
        acc[0] = fmaf(p01.x, vv, acc[0]);
        acc[1] = fmaf(p01.y, vv, acc[1]);
        acc[2] = fmaf(p23.x, vv, acc[2]);
        acc[3] = fmaf(p23.y, vv, acc[3]);
        acc[4] = fmaf(p45.x, vv, acc[4]);
        acc[5] = fmaf(p45.y, vv, acc[5]);
    }
#pragma unroll
    for (int up = 0; up < 6; up++) {
        int u = g * 6 + up;
        part_acc[((size_t)(bh * NTOP + u) * NCH + c) * 64 + d] = acc[up];
    }
}

// merge 16 chunk partials per (bh,u); scatter bf16 into pre_h
__global__ __launch_bounds__(256)
void attn_merge_kernel(const float* __restrict__ part_m, const float* __restrict__ part_s,
                       const float* __restrict__ part_acc, const int* __restrict__ mtop,
                       unsigned short* __restrict__ pre_h) {
    int ug = blockIdx.x;
    int bh = blockIdx.y;
    int b = bh >> 3, h = bh & 7;
    int tid = threadIdx.x;
    int u = ug * 4 + (tid >> 6);
    int d = tid & 63;
    int base = (bh * NTOP + u) * NCH;
    float m = -1e30f;
#pragma unroll
    for (int c = 0; c < NCH; c++) m = fmaxf(m, part_m[base + c]);
    float s = 0.f, o = 0.f;
#pragma unroll
    for (int c = 0; c < NCH; c++) {
        float w = __expf(part_m[base + c] - m);
        s += part_s[base + c] * w;
        o = fmaf(part_acc[(size_t)(base + c) * 64 + d], w, o);
    }
    o /= s;
    int iq = mtop[bh * NTOP + u];
    pre_h[((size_t)b * L + iq) * DM + h * DH + d] = f2bf(o);
}

extern "C" void kernel_launch(void* const* d_in, const int* in_sizes, int n_in,
                              void* d_out, int out_size, void* d_ws, size_t ws_size,
                              hipStream_t stream) {
    const float* queries = (const float*)d_in[0];
    const float* keys    = (const float*)d_in[1];
    const float* values  = (const float*)d_in[2];
    const float* pad     = (const float*)d_in[3];
    const float* Wq = (const float*)d_in[4];  const float* bq = (const float*)d_in[5];
    const float* Wk = (const float*)d_in[6];  const float* bk = (const float*)d_in[7];
    const float* Wv = (const float*)d_in[8];  const float* bv = (const float*)d_in[9];
    const float* Wf = (const float*)d_in[10]; const float* bfv = (const float*)d_in[11];
    const float* qlnw = (const float*)d_in[12]; const float* qlnb = (const float*)d_in[13];
    const float* flnw = (const float*)d_in[14]; const float* flnb = (const float*)d_in[15];
    const int* idx = (const int*)d_in[16];

    float* ws = (float*)d_ws;
    const size_t NE = (size_t)B_ * L * DM;   // 8388608
    float* qb    = ws;
    float* kb    = ws + NE;
    float* vb    = ws + 2 * NE;
    float* spare = ws + 3 * NE;                      // (unused f32 slot)
    float* Mbuf  = ws + 4 * NE;                      // 64*2048
    float* denom = Mbuf + (size_t)B_ * H_ * L;       // 8*2048
    float* csum  = denom + (size_t)B_ * L;           // 8*32*512
    int*   mtop  = (int*)(csum + (size_t)B_ * VC * DM);
    unsigned short* bfr = (unsigned short*)(mtop + 2048);
    unsigned short* keys_h = bfr;
    unsigned short* keys_l = bfr + NE;
    unsigned short* vals_h = bfr + 2 * NE;
    unsigned short* wts    = bfr + 3 * NE;
    unsigned short* wq_h = wts;              unsigned short* wq_l = wts + 262144;
    unsigned short* wk_h = wts + 2 * 262144; unsigned short* wk_l = wts + 3 * 262144;
    unsigned short* wv_h = wts + 4 * 262144; unsigned short* wv_l = wts + 5 * 262144;
    unsigned short* wf_h = wts + 6 * 262144; unsigned short* wf_l = wts + 7 * 262144;
    unsigned short* pre_h = keys_h;          // alias: keys dead after k-GEMM

    float* tmp = (float*)d_out;
    unsigned short* lnq_h = (unsigned short*)d_out;   // d_out as bf16 scratch
    unsigned short* lnq_l = lnq_h + NE;
    float* part_m   = tmp;                            // later: attn partials
    float* part_s   = part_m + 64 * NTOP * NCH;
    float* part_acc = part_s + 64 * NTOP * NCH;

    padscan_kernel<<<B_, 256, 0, stream>>>(pad, denom);
    ln_split_kernel<<<B_ * L, 256, 0, stream>>>(queries, qlnw, qlnb, lnq_h, lnq_l);
    split2_kernel<<<NE / 1024, 256, 0, stream>>>(keys, keys_h, keys_l);
    split1_kernel<<<NE / 1024, 256, 0, stream>>>(values, vals_h);
    dim3 gw(16, 16);
    wsplit_kernel<<<gw, 256, 0, stream>>>(Wq, wq_h, wq_l);
    wsplit_kernel<<<gw, 256, 0, stream>>>(Wk, wk_h, wk_l);
    wsplit_kernel<<<gw, 256, 0, stream>>>(Wv, wv_h, wv_l);
    wsplit_kernel<<<gw, 256, 0, stream>>>(Wf, wf_h, wf_l);

    dim3 gg(4, 128);
    gemm_mfma<3><<<gg, 256, 0, stream>>>(lnq_h, lnq_l, wq_h, wq_l, bq, qb);
    gemm_mfma<3><<<gg, 256, 0, stream>>>(keys_h, keys_l, wk_h, wk_l, bk, kb);
    gemm_mfma<2><<<gg, 256, 0, stream>>>(vals_h, nullptr, wv_h, wv_l, bv, vb);

    sample_m_kernel<<<B_ * L / 4, 256, 0, stream>>>(qb, kb, idx, Mbuf);
    topk_kernel<<<B_ * H_, 256, 0, stream>>>(Mbuf, mtop);
    dim3 gv(VC, B_, 2);
    vsum_kernel<<<gv, 256, 0, stream>>>(vb, csum);
    vavg_kernel<<<gv, 256, 0, stream>>>(vb, csum, denom, pre_h);
    dim3 gc(NCH, 64);
    attn_chunk_kernel<<<gc, 256, 0, stream>>>(qb, kb, vb, mtop, pad,
                                              part_m, part_s, part_acc);
    dim3 gmg(6, 64);
    attn_merge_kernel<<<gmg, 256, 0, stream>>>(part_m, part_s, part_acc, mtop, pre_h);
    gemm_mfma<2><<<gg, 256, 0, stream>>>(pre_h, nullptr, wf_h, wf_l, bfv, (float*)d_out);
    ln_kernel<<<B_ * L, 256, 0, stream>>>((float*)d_out, flnw, flnb, (float*)d_out);
}

// Round 6
// 303.140 us; speedup vs baseline: 2.7418x; 1.0665x over previous
//
#include <hip/hip_runtime.h>
#include <math.h>

#define L 2048
#define DM 512
#define B_ 8
#define H_ 8
#define DH 64
#define SK 24
#define NTOP 24
#define CHUNK 128
#define NCH (L / CHUNK)   // 16
#define VC 32             // vavg chunks
#define VR 64             // rows per vavg chunk

typedef __attribute__((ext_vector_type(8))) short short8;
typedef __attribute__((ext_vector_type(8))) __bf16 bf16x8;
typedef __attribute__((ext_vector_type(4))) float f32x4;

__device__ inline unsigned short f2bf(float x) {
    unsigned u = __float_as_uint(x);
    unsigned r = (u + 0x7FFFu + ((u >> 16) & 1u)) >> 16;
    return (unsigned short)r;
}
__device__ inline float bf2f(unsigned short h) {
    return __uint_as_float(((unsigned)h) << 16);
}

__device__ inline f32x4 MFMA_BF16(short8 a, short8 b, f32x4 c) {
    return __builtin_amdgcn_mfma_f32_16x16x32_bf16(
        __builtin_bit_cast(bf16x8, a), __builtin_bit_cast(bf16x8, b), c, 0, 0, 0);
}

// ---------------- reduce helpers ----------------
__device__ inline float waveReduceSum(float v) {
    for (int o = 32; o > 0; o >>= 1) v += __shfl_down(v, o, 64);
    return v;
}
__device__ inline float waveReduceMax(float v) {
    for (int o = 32; o > 0; o >>= 1) v = fmaxf(v, __shfl_down(v, o, 64));
    return v;
}

// ---------------- LayerNorm (row-wise, 512 cols) f32 out ----------------
__global__ __launch_bounds__(256)
void ln_kernel(const float* __restrict__ x, const float* __restrict__ w,
               const float* __restrict__ bvec, float* __restrict__ out) {
    int row = blockIdx.x;
    const float* xr = x + (size_t)row * DM;
    float* orow = out + (size_t)row * DM;
    int tid = threadIdx.x;
    float2 v = *(const float2*)(xr + tid * 2);
    float s = v.x + v.y;
    float sq = v.x * v.x + v.y * v.y;
    __shared__ float red[8];
    float ws = waveReduceSum(s);
    float wq = waveReduceSum(sq);
    int wid = tid >> 6, lane = tid & 63;
    if (lane == 0) { red[wid] = ws; red[4 + wid] = wq; }
    __syncthreads();
    float tot = red[0] + red[1] + red[2] + red[3];
    float totq = red[4] + red[5] + red[6] + red[7];
    float mean = tot * (1.0f / DM);
    float var = totq * (1.0f / DM) - mean * mean;
    float inv = rsqrtf(var + 1e-8f);
    float w0 = w[tid * 2], w1 = w[tid * 2 + 1];
    float b0 = bvec[tid * 2], b1 = bvec[tid * 2 + 1];
    float2 o;
    o.x = w0 * (v.x - mean) * inv + b0;
    o.y = w1 * (v.y - mean) * inv + b1;
    *(float2*)(orow + tid * 2) = o;
}

// ---------------- LayerNorm with bf16 hi/lo split output ----------------
__global__ __launch_bounds__(256)
void ln_split_kernel(const float* __restrict__ x, const float* __restrict__ w,
                     const float* __restrict__ bvec,
                     unsigned short* __restrict__ oh, unsigned short* __restrict__ ol) {
    int row = blockIdx.x;
    const float* xr = x + (size_t)row * DM;
    int tid = threadIdx.x;
    float2 v = *(const float2*)(xr + tid * 2);
    float s = v.x + v.y;
    float sq = v.x * v.x + v.y * v.y;
    __shared__ float red[8];
    float ws = waveReduceSum(s);
    float wq = waveReduceSum(sq);
    int wid = tid >> 6, lane = tid & 63;
    if (lane == 0) { red[wid] = ws; red[4 + wid] = wq; }
    __syncthreads();
    float tot = red[0] + red[1] + red[2] + red[3];
    float totq = red[4] + red[5] + red[6] + red[7];
    float mean = tot * (1.0f / DM);
    float var = totq * (1.0f / DM) - mean * mean;
    float inv = rsqrtf(var + 1e-8f);
    float w0 = w[tid * 2], w1 = w[tid * 2 + 1];
    float b0 = bvec[tid * 2], b1 = bvec[tid * 2 + 1];
    float o0 = w0 * (v.x - mean) * inv + b0;
    float o1 = w1 * (v.y - mean) * inv + b1;
    ushort2 hh, ll;
    hh.x = f2bf(o0); ll.x = f2bf(o0 - bf2f(hh.x));
    hh.y = f2bf(o1); ll.y = f2bf(o1 - bf2f(hh.y));
    *(ushort2*)(oh + (size_t)row * DM + tid * 2) = hh;
    *(ushort2*)(ol + (size_t)row * DM + tid * 2) = ll;
}

// ---------------- hi/lo split (full) ----------------
__global__ __launch_bounds__(256)
void split2_kernel(const float* __restrict__ x, unsigned short* __restrict__ hi,
                   unsigned short* __restrict__ lo) {
    int i = blockIdx.x * 256 + threadIdx.x;
    float4 v = *(const float4*)(x + (size_t)i * 4);
    ushort4 h, l;
    h.x = f2bf(v.x); l.x = f2bf(v.x - bf2f(h.x));
    h.y = f2bf(v.y); l.y = f2bf(v.y - bf2f(h.y));
    h.z = f2bf(v.z); l.z = f2bf(v.z - bf2f(h.z));
    h.w = f2bf(v.w); l.w = f2bf(v.w - bf2f(h.w));
    *(ushort4*)(hi + (size_t)i * 4) = h;
    *(ushort4*)(lo + (size_t)i * 4) = l;
}

// ---------------- hi-only split ----------------
__global__ __launch_bounds__(256)
void split1_kernel(const float* __restrict__ x, unsigned short* __restrict__ hi) {
    int i = blockIdx.x * 256 + threadIdx.x;
    float4 v = *(const float4*)(x + (size_t)i * 4);
    ushort4 h;
    h.x = f2bf(v.x); h.y = f2bf(v.y); h.z = f2bf(v.z); h.w = f2bf(v.w);
    *(ushort4*)(hi + (size_t)i * 4) = h;
}

// ---------------- W transpose + hi/lo split: Wt[n][k] = W[k][n] ----------------
__global__ __launch_bounds__(256)
void wsplit_kernel(const float* __restrict__ W, unsigned short* __restrict__ th,
                   unsigned short* __restrict__ tl) {
    __shared__ float ts[32][33];
    int k0 = blockIdx.y * 32, n0 = blockIdx.x * 32;
    int t = threadIdx.x;
    int r = t >> 3, c = (t & 7) * 4;
    float4 v = *(const float4*)(W + (size_t)(k0 + r) * 512 + n0 + c);
    ts[r][c] = v.x; ts[r][c + 1] = v.y; ts[r][c + 2] = v.z; ts[r][c + 3] = v.w;
    __syncthreads();
    float a0 = ts[c + 0][r], a1 = ts[c + 1][r], a2 = ts[c + 2][r], a3 = ts[c + 3][r];
    ushort4 h, l;
    h.x = f2bf(a0); l.x = f2bf(a0 - bf2f(h.x));
    h.y = f2bf(a1); l.y = f2bf(a1 - bf2f(h.y));
    h.z = f2bf(a2); l.z = f2bf(a2 - bf2f(h.z));
    h.w = f2bf(a3); l.w = f2bf(a3 - bf2f(h.w));
    *(ushort4*)(th + (size_t)(n0 + r) * 512 + k0 + c) = h;
    *(ushort4*)(tl + (size_t)(n0 + r) * 512 + k0 + c) = l;
}

// ---------------- MFMA split GEMM: C[16384 x 512] = A @ W + bias ----------------
// OMODE: 0 = f32 only, 1 = f32 + bf16 mirror, 2 = bf16 only
template<int TERMS, int OMODE>
__global__ __launch_bounds__(256, 2)
void gemm_mfma(const unsigned short* __restrict__ Ah, const unsigned short* __restrict__ Al,
               const unsigned short* __restrict__ Bh, const unsigned short* __restrict__ Bl,
               const float* __restrict__ bias, float* __restrict__ C,
               unsigned short* __restrict__ Ch) {
    __shared__ __align__(16) unsigned short smem[20480];  // 40KB
    unsigned short* sAh = smem;              // [128][40]
    unsigned short* sAl = smem + 5120;
    unsigned short* sBh = smem + 10240;
    unsigned short* sBl = smem + 15360;

    int orig = blockIdx.x + 4 * blockIdx.y;          // 512 blocks
    int j = (orig & 7) * 64 + (orig >> 3);
    int n0 = (j & 3) * 128, m0 = (j >> 2) * 128;

    int tid = threadIdx.x;
    int lane = tid & 63, wv = tid >> 6;
    int wr = wv >> 1, wc = wv & 1;
    int lrow = lane & 15;
    int kofs = (lane >> 4) * 8;

    int f0 = tid, f1 = tid + 256;
    int row0 = f0 >> 2, c0 = (f0 & 3) * 8;
    int row1 = f1 >> 2, c1 = (f1 & 3) * 8;

    f32x4 acc[4][4];
#pragma unroll
    for (int mf = 0; mf < 4; mf++)
#pragma unroll
        for (int nf = 0; nf < 4; nf++) acc[mf][nf] = (f32x4){0.f, 0.f, 0.f, 0.f};

    short8 rAh0, rAh1, rAl0, rAl1, rBh0, rBh1, rBl0, rBl1;

    auto LOAD = [&](int kt) {
        int k0 = kt * 32;
        rAh0 = *(const short8*)(Ah + (size_t)(m0 + row0) * 512 + k0 + c0);
        rAh1 = *(const short8*)(Ah + (size_t)(m0 + row1) * 512 + k0 + c1);
        if (TERMS == 3) {
            rAl0 = *(const short8*)(Al + (size_t)(m0 + row0) * 512 + k0 + c0);
            rAl1 = *(const short8*)(Al + (size_t)(m0 + row1) * 512 + k0 + c1);
        }
        rBh0 = *(const short8*)(Bh + (size_t)(n0 + row0) * 512 + k0 + c0);
        rBh1 = *(const short8*)(Bh + (size_t)(n0 + row1) * 512 + k0 + c1);
        rBl0 = *(const short8*)(Bl + (size_t)(n0 + row0) * 512 + k0 + c0);
        rBl1 = *(const short8*)(Bl + (size_t)(n0 + row1) * 512 + k0 + c1);
    };
    auto STORE = [&]() {
        *(short8*)&sAh[row0 * 40 + c0] = rAh0;
        *(short8*)&sAh[row1 * 40 + c1] = rAh1;
        if (TERMS == 3) {
            *(short8*)&sAl[row0 * 40 + c0] = rAl0;
            *(short8*)&sAl[row1 * 40 + c1] = rAl1;
        }
        *(short8*)&sBh[row0 * 40 + c0] = rBh0;
        *(short8*)&sBh[row1 * 40 + c1] = rBh1;
        *(short8*)&sBl[row0 * 40 + c0] = rBl0;
        *(short8*)&sBl[row1 * 40 + c1] = rBl1;
    };

    int abase = (wr * 64 + lrow) * 40 + kofs;
    int bbase = (wc * 64 + lrow) * 40 + kofs;

    LOAD(0);
    for (int kt = 0; kt < 16; kt++) {
        STORE();
        __syncthreads();
        if (kt < 15) LOAD(kt + 1);
        short8 ah[4], al[4], bh[4], bl[4];
#pragma unroll
        for (int mf = 0; mf < 4; mf++) {
            ah[mf] = *(const short8*)&sAh[abase + mf * 640];
            if (TERMS == 3) al[mf] = *(const short8*)&sAl[abase + mf * 640];
        }
#pragma unroll
        for (int nf = 0; nf < 4; nf++) {
            bh[nf] = *(const short8*)&sBh[bbase + nf * 640];
            bl[nf] = *(const short8*)&sBl[bbase + nf * 640];
        }
#pragma unroll
        for (int mf = 0; mf < 4; mf++)
#pragma unroll
            for (int nf = 0; nf < 4; nf++) {
                acc[mf][nf] = MFMA_BF16(ah[mf], bh[nf], acc[mf][nf]);
                acc[mf][nf] = MFMA_BF16(ah[mf], bl[nf], acc[mf][nf]);
                if (TERMS == 3) acc[mf][nf] = MFMA_BF16(al[mf], bh[nf], acc[mf][nf]);
            }
        __syncthreads();
    }

    int crow0 = m0 + wr * 64 + (lane >> 4) * 4;
    int ccol0 = n0 + wc * 64 + lrow;
    float bb[4];
#pragma unroll
    for (int nf = 0; nf < 4; nf++) bb[nf] = bias[ccol0 + nf * 16];
#pragma unroll
    for (int mf = 0; mf < 4; mf++)
#pragma unroll
        for (int nf = 0; nf < 4; nf++)
#pragma unroll
            for (int r = 0; r < 4; r++) {
                float val = acc[mf][nf][r] + bb[nf];
                size_t idx = (size_t)(crow0 + mf * 16 + r) * 512 + ccol0 + nf * 16;
                if (OMODE != 2) C[idx] = val;
                if (OMODE != 0) Ch[idx] = f2bf(val);
            }
}

// ---------------- sampled QK^T -> M (one wave per (b,i), full-row gathers) ----------------
__global__ __launch_bounds__(256)
void sample_m_kernel(const float* __restrict__ q, const float* __restrict__ k,
                     const int* __restrict__ idx, float* __restrict__ M) {
    int bid = blockIdx.x;          // 4096
    int b = bid & 7;
    int ig = bid >> 3;             // 0..511
    int wv = threadIdx.x >> 6, lane = threadIdx.x & 63;
    int i = ig * 4 + wv;
    const float* qrow = q + ((size_t)b * L + i) * DM + lane * 8;
    float4 q0 = *(const float4*)qrow;
    float4 q1 = *(const float4*)(qrow + 4);
    int myidx = 0;
    if (lane < SK) myidx = idx[i * SK + lane];
    float mx = -1e30f, sm = 0.f;
#pragma unroll
    for (int j = 0; j < SK; j++) {
        int row = __shfl(myidx, j, 64);
        const float* kp = k + ((size_t)b * L + row) * DM + lane * 8;
        float4 k0 = *(const float4*)kp;
        float4 k1 = *(const float4*)(kp + 4);
        float s = q0.x * k0.x + q0.y * k0.y + q0.z * k0.z + q0.w * k0.w
                + q1.x * k1.x + q1.y * k1.y + q1.z * k1.z + q1.w * k1.w;
        s += __shfl_xor(s, 1, 64);
        s += __shfl_xor(s, 2, 64);
        s += __shfl_xor(s, 4, 64);
        mx = fmaxf(mx, s);
        sm += s;
    }
    if ((lane & 7) == 0) {
        int h = lane >> 3;
        M[((size_t)b * H_ + h) * L + i] = mx - sm * (1.0f / L);
    }
}

// ---------------- top-24 per (b,h), low-index tie-break ----------------
__global__ __launch_bounds__(256)
void topk_kernel(const float* __restrict__ M, int* __restrict__ mtop) {
    int bh = blockIdx.x;
    __shared__ float vals[L];
    __shared__ float rv[4];
    __shared__ int ri[4];
    int tid = threadIdx.x;
    const float* Mr = M + (size_t)bh * L;
    for (int t = tid; t < L; t += 256) vals[t] = Mr[t];
    __syncthreads();
    for (int it = 0; it < NTOP; it++) {
        float bv = -1e30f; int bi = 0x7fffffff;
        for (int t = tid; t < L; t += 256) {
            float v = vals[t];
            if (v > bv || (v == bv && t < bi)) { bv = v; bi = t; }
        }
        for (int o = 32; o > 0; o >>= 1) {
            float ov = __shfl_down(bv, o, 64);
            int oi = __shfl_down(bi, o, 64);
            if (ov > bv || (ov == bv && oi < bi)) { bv = ov; bi = oi; }
        }
        int wid = tid >> 6, lane = tid & 63;
        if (lane == 0) { rv[wid] = bv; ri[wid] = bi; }
        __syncthreads();
        if (tid == 0) {
            float fbv = rv[0]; int fbi = ri[0];
            for (int wv = 1; wv < 4; wv++)
                if (rv[wv] > fbv || (rv[wv] == fbv && ri[wv] < fbi)) { fbv = rv[wv]; fbi = ri[wv]; }
            mtop[bh * NTOP + it] = fbi;
            vals[fbi] = -1e30f;
        }
        __syncthreads();
    }
}

// ---------------- padding cumsum ----------------
__global__ __launch_bounds__(256)
void padscan_kernel(const float* __restrict__ pad, float* __restrict__ denom) {
    int b = blockIdx.x;
    __shared__ float tot[256];
    int tid = threadIdx.x;
    const float* p = pad + (size_t)b * L;
    float loc[8];
    float s = 0.f;
#pragma unroll
    for (int u = 0; u < 8; u++) { s += p[tid * 8 + u]; loc[u] = s; }
    tot[tid] = s;
    __syncthreads();
    for (int off = 1; off < 256; off <<= 1) {
        float add = (tid >= off) ? tot[tid - off] : 0.f;
        __syncthreads();
        tot[tid] += add;
        __syncthreads();
    }
    float excl = tot[tid] - s;
#pragma unroll
    for (int u = 0; u < 8; u++) denom[(size_t)b * L + tid * 8 + u] = excl + loc[u];
}

// ---------------- cumulative average of V (bf16 in, 2 passes) ----------------
__global__ __launch_bounds__(256)
void vsum_kernel(const unsigned short* __restrict__ vh, float* __restrict__ csum) {
    int c = blockIdx.x, b = blockIdx.y;
    int d2 = threadIdx.x;
    size_t base = ((size_t)b * L + c * VR) * DM + d2 * 2;
    float a0 = 0.f, a1 = 0.f;
    for (int t = 0; t < VR; t++) {
        unsigned v = *(const unsigned*)(vh + base + (size_t)t * DM);
        a0 += bf2f((unsigned short)(v & 0xffff));
        a1 += bf2f((unsigned short)(v >> 16));
    }
    float2 st = {a0, a1};
    *(float2*)(csum + ((size_t)b * VC + c) * DM + d2 * 2) = st;
}

__global__ __launch_bounds__(256)
void vavg_kernel(const unsigned short* __restrict__ vh, const float* __restrict__ csum,
                 const float* __restrict__ denom, unsigned short* __restrict__ out_h) {
    int c = blockIdx.x, b = blockIdx.y;
    int d2 = threadIdx.x;
    float a0 = 0.f, a1 = 0.f;
    for (int cc = 0; cc < c; cc++) {
        float2 t = *(const float2*)(csum + ((size_t)b * VC + cc) * DM + d2 * 2);
        a0 += t.x; a1 += t.y;
    }
    size_t base = ((size_t)b * L + c * VR) * DM + d2 * 2;
    for (int t = 0; t < VR; t++) {
        unsigned v = *(const unsigned*)(vh + base + (size_t)t * DM);
        a0 += bf2f((unsigned short)(v & 0xffff));
        a1 += bf2f((unsigned short)(v >> 16));
        float dn = denom[(size_t)b * L + c * VR + t] + 1e-12f;
        unsigned o = (unsigned)f2bf(a0 / dn) | ((unsigned)f2bf(a1 / dn) << 16);
        *(unsigned*)(out_h + base + (size_t)t * DM) = o;
    }
}

// ---------------- Q gather + pre-scale + lim prep ----------------
__global__ __launch_bounds__(256)
void qprep_kernel(const float* __restrict__ qb, const int* __restrict__ mtop,
                  const float* __restrict__ pad, unsigned short* __restrict__ qsel,
                  int* __restrict__ lim_arr) {
    int bh = blockIdx.x; int b = bh >> 3, h = bh & 7;
    int tid = threadIdx.x;
#pragma unroll
    for (int l = 0; l < 2; l++) {
        int f = tid + l * 256;        // 0..511
        int u = f >> 4, seg = (f & 15) * 4;
        ushort4 o;
        if (u < NTOP) {
            int iq = mtop[bh * NTOP + u];
            bool ok = pad[(size_t)b * L + iq] != 0.f;
            float sc = ok ? 0.044194173824159216f : 0.f;
            float4 qv = *(const float4*)(qb + ((size_t)b * L + iq) * DM + h * DH + seg);
            o.x = f2bf(qv.x * sc); o.y = f2bf(qv.y * sc);
            o.z = f2bf(qv.z * sc); o.w = f2bf(qv.w * sc);
            if (seg == 0) lim_arr[bh * 32 + u] = ok ? iq : (L - 1);
        } else {
            o.x = o.y = o.z = o.w = 0;
            if (seg == 0) lim_arr[bh * 32 + u] = -1;
        }
        *(ushort4*)(qsel + ((size_t)bh * 32 + u) * 64 + seg) = o;
    }
}

// ---------------- MFMA split-chunk sparse attention ----------------
// Block (c, bh). K/V bf16 from GEMM mirrors; Q pre-gathered/scaled bf16.
// QK^T: 16x16x32 MFMA, C[u][j]. PV: O^T = V^T x P^T, C[d][u].
__global__ __launch_bounds__(256)
void attn_chunk_mfma(const unsigned short* __restrict__ kbh,
                     const unsigned short* __restrict__ vbh,
                     const unsigned short* __restrict__ qsel,
                     const int* __restrict__ lim_arr,
                     float* __restrict__ part_m, float* __restrict__ part_s,
                     float* __restrict__ part_acc) {
    int c = blockIdx.x, bh = blockIdx.y;
    int b = bh >> 3, h = bh & 7;
    int j0 = c * CHUNK;
    __shared__ __align__(16) unsigned short KV[128 * 64];  // 16KB swizzled (K then V)
    __shared__ __align__(16) unsigned short Ps[32 * 128];  // 8KB swizzled
    __shared__ __align__(16) unsigned short Qs[32 * 64];   // 4KB swizzled
    __shared__ float redm[4][32];
    __shared__ float reds[4][32];
    __shared__ int lims[32];

    int tid = threadIdx.x;
    int wv = tid >> 6, lane = tid & 63;
    int l15 = lane & 15, g = lane >> 4;

    // ---- stage K (global b128 -> LDS b128, block-XOR swizzle) ----
    const unsigned short* kpanel = kbh + ((size_t)b * L + j0) * DM + h * DH;
    short8 kreg[4];
#pragma unroll
    for (int l = 0; l < 4; l++) {
        int f = tid + l * 256;
        int jr = f >> 3, blk = f & 7;
        kreg[l] = *(const short8*)(kpanel + (size_t)jr * DM + blk * 8);
    }
    {
        int u = tid >> 3, blk = tid & 7;
        short8 qreg = *(const short8*)(qsel + ((size_t)bh * 32 + u) * 64 + blk * 8);
        *(short8*)&Qs[u * 64 + (((blk ^ (u & 7))) << 3)] = qreg;
    }
#pragma unroll
    for (int l = 0; l < 4; l++) {
        int f = tid + l * 256;
        int jr = f >> 3, blk = f & 7;
        *(short8*)&KV[jr * 64 + ((blk ^ (jr & 7)) << 3)] = kreg[l];
    }
    if (tid < 32) lims[tid] = lim_arr[bh * 32 + tid];
    __syncthreads();

    // ---- QK^T: wave wv owns keys j = wv*32 + {0..31} ----
    f32x4 sf[2][2];
#pragma unroll
    for (int mf = 0; mf < 2; mf++)
#pragma unroll
        for (int nf = 0; nf < 2; nf++) sf[mf][nf] = (f32x4){0.f, 0.f, 0.f, 0.f};
#pragma unroll
    for (int ks = 0; ks < 2; ks++) {
        short8 aq[2], bk[2];
#pragma unroll
        for (int mf = 0; mf < 2; mf++) {
            int u = mf * 16 + l15;
            int blk = (ks * 4 + g) ^ (u & 7);
            aq[mf] = *(const short8*)&Qs[u * 64 + (blk << 3)];
        }
#pragma unroll
        for (int nf = 0; nf < 2; nf++) {
            int jr = wv * 32 + nf * 16 + l15;
            int blk = (ks * 4 + g) ^ (jr & 7);
            bk[nf] = *(const short8*)&KV[jr * 64 + (blk << 3)];
        }
#pragma unroll
        for (int mf = 0; mf < 2; mf++)
#pragma unroll
            for (int nf = 0; nf < 2; nf++)
                sf[mf][nf] = MFMA_BF16(aq[mf], bk[nf], sf[mf][nf]);
    }

    // ---- issue V global loads early (hide under softmax) ----
    const unsigned short* vpanel = vbh + ((size_t)b * L + j0) * DM + h * DH;
    short8 vreg[4];
#pragma unroll
    for (int l = 0; l < 4; l++) {
        int f = tid + l * 256;
        int jr = f >> 3, blk = f & 7;
        vreg[l] = *(const short8*)(vpanel + (size_t)jr * DM + blk * 8);
    }

    // ---- mask + wave-local max per u ----
    float sv[2][2][4];
    float mx[2][4];
#pragma unroll
    for (int mf = 0; mf < 2; mf++)
#pragma unroll
        for (int r = 0; r < 4; r++) {
            int u = mf * 16 + g * 4 + r;
            int limv = lims[u];
            float m = -1e30f;
#pragma unroll
            for (int nf = 0; nf < 2; nf++) {
                int jg = j0 + wv * 32 + nf * 16 + l15;
                float s = (jg <= limv) ? sf[mf][nf][r] : -1e30f;
                sv[mf][nf][r] = s;
                m = fmaxf(m, s);
            }
            m = fmaxf(m, __shfl_xor(m, 1, 64));
            m = fmaxf(m, __shfl_xor(m, 2, 64));
            m = fmaxf(m, __shfl_xor(m, 4, 64));
            m = fmaxf(m, __shfl_xor(m, 8, 64));
            mx[mf][r] = m;
        }
    if (l15 == 0) {
#pragma unroll
        for (int mf = 0; mf < 2; mf++)
#pragma unroll
            for (int r = 0; r < 4; r++)
                redm[wv][mf * 16 + g * 4 + r] = mx[mf][r];
    }
    __syncthreads();   // K reads done by all waves; redm complete

    // ---- chunk max, exp, P write, wave sums ----
    float lmax[2][4], smv[2][4];
#pragma unroll
    for (int mf = 0; mf < 2; mf++)
#pragma unroll
        for (int r = 0; r < 4; r++) {
            int u = mf * 16 + g * 4 + r;
            float m = fmaxf(fmaxf(redm[0][u], redm[1][u]),
                            fmaxf(redm[2][u], redm[3][u]));
            lmax[mf][r] = m;
            bool any = m > -1e29f;
            float sm = 0.f;
#pragma unroll
            for (int nf = 0; nf < 2; nf++) {
                float e = any ? __expf(sv[mf][nf][r] - m) : 0.f;
                sm += e;
                int jr = wv * 32 + nf * 16 + l15;
                Ps[u * 128 + (((jr >> 3) ^ (u & 7)) << 3) + (jr & 7)] = f2bf(e);
            }
            sm += __shfl_xor(sm, 1, 64);
            sm += __shfl_xor(sm, 2, 64);
            sm += __shfl_xor(sm, 4, 64);
            sm += __shfl_xor(sm, 8, 64);
            smv[mf][r] = sm;
        }
    if (l15 == 0) {
#pragma unroll
        for (int mf = 0; mf < 2; mf++)
#pragma unroll
            for (int r = 0; r < 4; r++)
                reds[wv][mf * 16 + g * 4 + r] = smv[mf][r];
    }
    // ---- stage V into KV (half-swap swizzle for strided u16 reads) ----
#pragma unroll
    for (int l = 0; l < 4; l++) {
        int f = tid + l * 256;
        int jr = f >> 3, blk = f & 7;
        short8 w = vreg[l];
        if ((jr >> 3) & 1) w = __builtin_shufflevector(w, w, 4, 5, 6, 7, 0, 1, 2, 3);
        *(short8*)&KV[jr * 64 + ((blk ^ (jr & 7)) << 3)] = w;
    }
    __syncthreads();   // P, V, reds complete

    // wave 0 writes part_m / part_s
    if (wv == 0 && l15 == 0) {
#pragma unroll
        for (int mf = 0; mf < 2; mf++)
#pragma unroll
            for (int r = 0; r < 4; r++) {
                int u = mf * 16 + g * 4 + r;
                if (u < NTOP) {
                    float ss = reds[0][u] + reds[1][u] + reds[2][u] + reds[3][u];
                    part_m[(bh * NTOP + u) * NCH + c] = lmax[mf][r];
                    part_s[(bh * NTOP + u) * NCH + c] = ss;
                }
            }
    }

    // ---- PV: O^T = V^T x P^T. Wave wv owns d in [wv*16, wv*16+16) ----
    f32x4 of[2];
    of[0] = (f32x4){0.f, 0.f, 0.f, 0.f};
    of[1] = (f32x4){0.f, 0.f, 0.f, 0.f};
    int d = wv * 16 + l15;
#pragma unroll
    for (int ks = 0; ks < 4; ks++) {
        unsigned short va[8];
#pragma unroll
        for (int i = 0; i < 8; i++) {
            int jr = ks * 32 + g * 8 + i;
            int addr = jr * 64 + (((d >> 3) ^ (jr & 7)) << 3)
                     + ((d & 7) ^ (((jr >> 3) & 1) << 2));
            va[i] = KV[addr];
        }
        short8 av;
#pragma unroll
        for (int i = 0; i < 8; i++) av[i] = (short)va[i];
        short8 bp[2];
#pragma unroll
        for (int nf = 0; nf < 2; nf++) {
            int u = nf * 16 + l15;
            int blk = (ks * 4 + g) ^ (u & 7);
            bp[nf] = *(const short8*)&Ps[u * 128 + (blk << 3)];
        }
#pragma unroll
        for (int nf = 0; nf < 2; nf++)
            of[nf] = MFMA_BF16(av, bp[nf], of[nf]);
    }
#pragma unroll
    for (int nf = 0; nf < 2; nf++) {
        int u = nf * 16 + l15;
        if (u < NTOP) {
#pragma unroll
            for (int r = 0; r < 4; r++)
                part_acc[((size_t)(bh * NTOP + u) * NCH + c) * 64 + wv * 16 + g * 4 + r] =
                    of[nf][r];
        }
    }
}

// merge 16 chunk partials per (bh,u); scatter bf16 into pre_h
__global__ __launch_bounds__(256)
void attn_merge_kernel(const float* __restrict__ part_m, const float* __restrict__ part_s,
                       const float* __restrict__ part_acc, const int* __restrict__ mtop,
                       unsigned short* __restrict__ pre_h) {
    int ug = blockIdx.x;
    int bh = blockIdx.y;
    int b = bh >> 3, h = bh & 7;
    int tid = threadIdx.x;
    int u = ug * 4 + (tid >> 6);
    int d = tid & 63;
    int base = (bh * NTOP + u) * NCH;
    float m = -1e30f;
#pragma unroll
    for (int c = 0; c < NCH; c++) m = fmaxf(m, part_m[base + c]);
    float s = 0.f, o = 0.f;
#pragma unroll
    for (int c = 0; c < NCH; c++) {
        float w = __expf(part_m[base + c] - m);
        s += part_s[base + c] * w;
        o = fmaf(part_acc[(size_t)(base + c) * 64 + d], w, o);
    }
    o /= s;
    int iq = mtop[bh * NTOP + u];
    pre_h[((size_t)b * L + iq) * DM + h * DH + d] = f2bf(o);
}

extern "C" void kernel_launch(void* const* d_in, const int* in_sizes, int n_in,
                              void* d_out, int out_size, void* d_ws, size_t ws_size,
                              hipStream_t stream) {
    const float* queries = (const float*)d_in[0];
    const float* keys    = (const float*)d_in[1];
    const float* values  = (const float*)d_in[2];
    const float* pad     = (const float*)d_in[3];
    const float* Wq = (const float*)d_in[4];  const float* bq = (const float*)d_in[5];
    const float* Wk = (const float*)d_in[6];  const float* bk = (const float*)d_in[7];
    const float* Wv = (const float*)d_in[8];  const float* bv = (const float*)d_in[9];
    const float* Wf = (const float*)d_in[10]; const float* bfv = (const float*)d_in[11];
    const float* qlnw = (const float*)d_in[12]; const float* qlnb = (const float*)d_in[13];
    const float* flnw = (const float*)d_in[14]; const float* flnb = (const float*)d_in[15];
    const int* idx = (const int*)d_in[16];

    float* ws = (float*)d_ws;
    const size_t NE = (size_t)B_ * L * DM;   // 8388608
    float* qb    = ws;
    float* kb    = ws + NE;
    unsigned short* vb_h = (unsigned short*)(ws + 2 * NE);   // NE u16
    unsigned short* kb_h = vb_h + NE;                        // NE u16 (fills the old vb f32 slot)
    unsigned short* qsel = (unsigned short*)(ws + 3 * NE);   // 64*32*64 u16
    int* lim_arr = (int*)(qsel + 64 * 32 * 64);              // 2048 ints
    float* Mbuf  = ws + 4 * NE;                      // 64*2048
    float* denom = Mbuf + (size_t)B_ * H_ * L;       // 8*2048
    float* csum  = denom + (size_t)B_ * L;           // 8*32*512
    int*   mtop  = (int*)(csum + (size_t)B_ * VC * DM);
    unsigned short* bfr = (unsigned short*)(mtop + 2048);
    unsigned short* keys_h = bfr;
    unsigned short* keys_l = bfr + NE;
    unsigned short* vals_h = bfr + 2 * NE;
    unsigned short* wts    = bfr + 3 * NE;
    unsigned short* wq_h = wts;              unsigned short* wq_l = wts + 262144;
    unsigned short* wk_h = wts + 2 * 262144; unsigned short* wk_l = wts + 3 * 262144;
    unsigned short* wv_h = wts + 4 * 262144; unsigned short* wv_l = wts + 5 * 262144;
    unsigned short* wf_h = wts + 6 * 262144; unsigned short* wf_l = wts + 7 * 262144;
    unsigned short* pre_h = keys_h;          // alias: keys dead after k-GEMM

    float* tmp = (float*)d_out;
    unsigned short* lnq_h = (unsigned short*)d_out;   // d_out as bf16 scratch
    unsigned short* lnq_l = lnq_h + NE;
    float* part_m   = tmp;                            // later: attn partials
    float* part_s   = part_m + 64 * NTOP * NCH;
    float* part_acc = part_s + 64 * NTOP * NCH;

    padscan_kernel<<<B_, 256, 0, stream>>>(pad, denom);
    ln_split_kernel<<<B_ * L, 256, 0, stream>>>(queries, qlnw, qlnb, lnq_h, lnq_l);
    split2_kernel<<<NE / 1024, 256, 0, stream>>>(keys, keys_h, keys_l);
    split1_kernel<<<NE / 1024, 256, 0, stream>>>(values, vals_h);
    dim3 gw(16, 16);
    wsplit_kernel<<<gw, 256, 0, stream>>>(Wq, wq_h, wq_l);
    wsplit_kernel<<<gw, 256, 0, stream>>>(Wk, wk_h, wk_l);
    wsplit_kernel<<<gw, 256, 0, stream>>>(Wv, wv_h, wv_l);
    wsplit_kernel<<<gw, 256, 0, stream>>>(Wf, wf_h, wf_l);

    dim3 gg(4, 128);
    gemm_mfma<3, 0><<<gg, 256, 0, stream>>>(lnq_h, lnq_l, wq_h, wq_l, bq, qb, nullptr);
    gemm_mfma<3, 1><<<gg, 256, 0, stream>>>(keys_h, keys_l, wk_h, wk_l, bk, kb, kb_h);
    gemm_mfma<2, 2><<<gg, 256, 0, stream>>>(vals_h, nullptr, wv_h, wv_l, bv, nullptr, vb_h);

    sample_m_kernel<<<B_ * L / 4, 256, 0, stream>>>(qb, kb, idx, Mbuf);
    topk_kernel<<<B_ * H_, 256, 0, stream>>>(Mbuf, mtop);
    qprep_kernel<<<64, 256, 0, stream>>>(qb, mtop, pad, qsel, lim_arr);
    dim3 gv(VC, B_);
    vsum_kernel<<<gv, 256, 0, stream>>>(vb_h, csum);
    vavg_kernel<<<gv, 256, 0, stream>>>(vb_h, csum, denom, pre_h);
    dim3 gc(NCH, 64);
    attn_chunk_mfma<<<gc, 256, 0, stream>>>(kb_h, vb_h, qsel, lim_arr,
                                            part_m, part_s, part_acc);
    dim3 gmg(6, 64);
    attn_merge_kernel<<<gmg, 256, 0, stream>>>(part_m, part_s, part_acc, mtop, pre_h);
    gemm_mfma<2, 0><<<gg, 256, 0, stream>>>(pre_h, nullptr, wf_h, wf_l, bfv, (float*)d_out, nullptr);
    ln_kernel<<<B_ * L, 256, 0, stream>>>((float*)d_out, flnw, flnb, (float*)d_out);
}